// Round 12
// baseline (3232.641 us; speedup 1.0000x reference)
//
#include <hip/hip_runtime.h>
#include <math.h>

constexpr int kB = 64, kN = 196, kENC = 2048, kDEC = 512, kE = 512, kATT = 512;
constexpr int kV = 32000, kT = 32, kTS = 31;
constexpr int kKIH = kE + kENC;        // 2560 (W_ih K)
constexpr int kKG  = kENC + kDEC;      // 2560 (per-step gates K: [ctx; h])
constexpr int kG   = 4 * kDEC;         // 2048
constexpr int kSPL = 8, kKSP = kKG / kSPL; // 320
constexpr int kM   = kTS * kB;         // 1984
constexpr int kMP  = 2048;

typedef __attribute__((ext_vector_type(8))) short bf8;
typedef __attribute__((ext_vector_type(4))) float f4;
typedef __attribute__((ext_vector_type(4))) unsigned u4;

__device__ __forceinline__ f4 mfma16(bf8 a, bf8 b, f4 c){
  asm("v_mfma_f32_16x16x32_bf16 %0, %1, %2, %0" : "+v"(c) : "v"(a), "v"(b));
  return c;
}
__device__ __forceinline__ float bf2f(unsigned short u){
  return __uint_as_float(((unsigned)u) << 16);
}
__device__ __forceinline__ unsigned short f2b(float f){
  unsigned u = __float_as_uint(f);
  u += 0x7fffu + ((u >> 16) & 1u);
  return (unsigned short)(u >> 16);
}
__device__ __forceinline__ float th_(float x){
  float e2 = __expf(2.f * x);
  return 1.f - 2.f * __builtin_amdgcn_rcpf(e2 + 1.f);
}
__device__ __forceinline__ float sg_(float x){
  return __builtin_amdgcn_rcpf(1.f + __expf(-x));
}

// ---------------- fp32 -> bf16 bulk convert ----------------
__global__ void k_cvt(const float* __restrict__ src, unsigned short* __restrict__ dst, int n8){
  int i = blockIdx.x * 256 + threadIdx.x;
  if (i >= n8) return;
  float4 a = ((const float4*)src)[2 * i];
  float4 b = ((const float4*)src)[2 * i + 1];
  union { unsigned short u[8]; uint4 v; } t;
  t.u[0] = f2b(a.x); t.u[1] = f2b(a.y); t.u[2] = f2b(a.z); t.u[3] = f2b(a.w);
  t.u[4] = f2b(b.x); t.u[5] = f2b(b.y); t.u[6] = f2b(b.z); t.u[7] = f2b(b.w);
  ((uint4*)dst)[i] = t.v;
}

// ------- features: fp32->bf16 convert + partial mean over n (fused) -------
__global__ __launch_bounds__(256) void k_cvtmean(const float* __restrict__ feat,
        unsigned short* __restrict__ featb, float* __restrict__ meanp){
  int b = blockIdx.x, nq = blockIdx.y, tid = threadIdx.x;
  int d0 = tid * 8;
  const float* fp = feat + (size_t)b * kN * kENC + d0;
  unsigned short* op = featb + (size_t)b * kN * kENC + d0;
  float s[8] = {0.f,0.f,0.f,0.f,0.f,0.f,0.f,0.f};
  int nbeg = nq * 49, nend = nbeg + 49;
  #pragma unroll 4
  for (int n = nbeg; n < nend; ++n){
    float4 a = *(const float4*)(fp + (size_t)n * kENC);
    float4 c = *(const float4*)(fp + (size_t)n * kENC + 4);
    union { unsigned short u[8]; u4 v; } t;
    t.u[0] = f2b(a.x); t.u[1] = f2b(a.y); t.u[2] = f2b(a.z); t.u[3] = f2b(a.w);
    t.u[4] = f2b(c.x); t.u[5] = f2b(c.y); t.u[6] = f2b(c.z); t.u[7] = f2b(c.w);
    *(u4*)(op + (size_t)n * kENC) = t.v;
    s[0] += a.x; s[1] += a.y; s[2] += a.z; s[3] += a.w;
    s[4] += c.x; s[5] += c.y; s[6] += c.z; s[7] += c.w;
  }
  float* mp = meanp + ((size_t)b * 4 + nq) * kENC + d0;
  #pragma unroll
  for (int j = 0; j < 8; j++) mp[j] = s[j];
}

// ---------------- fp32 [R][C] -> bf16 [C][R] ----------------
__global__ __launch_bounds__(256) void k_tcvt(const float* __restrict__ src,
                                              unsigned short* __restrict__ dst, int R, int C){
  __shared__ float t[32][33];
  int c0 = blockIdx.x * 32, r0 = blockIdx.y * 32;
  int tx = threadIdx.x & 31, ty = threadIdx.x >> 5;
  #pragma unroll
  for (int j = 0; j < 4; j++)
    t[ty + 8*j][tx] = src[(size_t)(r0 + ty + 8*j) * C + c0 + tx];
  __syncthreads();
  #pragma unroll
  for (int j = 0; j < 4; j++)
    dst[(size_t)(c0 + ty + 8*j) * R + r0 + tx] = f2b(t[tx][ty + 8*j]);
}

// ---------------- fp32 [R][C] -> fp32 [C][R] ----------------
__global__ __launch_bounds__(256) void k_tf32(const float* __restrict__ src,
                                              float* __restrict__ dst, int R, int C){
  __shared__ float t[32][33];
  int c0 = blockIdx.x * 32, r0 = blockIdx.y * 32;
  int tx = threadIdx.x & 31, ty = threadIdx.x >> 5;
  #pragma unroll
  for (int j = 0; j < 4; j++)
    t[ty + 8*j][tx] = src[(size_t)(r0 + ty + 8*j) * C + c0 + tx];
  __syncthreads();
  #pragma unroll
  for (int j = 0; j < 4; j++)
    dst[(size_t)(c0 + ty + 8*j) * R + r0 + tx] = t[tx][ty + 8*j];
}

// ---------------- h0 / c0 (sums 4 mean partials) ----------------
__global__ __launch_bounds__(512) void k_init(const float* __restrict__ meanp,
                       const float* __restrict__ Wh, const float* __restrict__ bh,
                       const float* __restrict__ Wc, const float* __restrict__ bc,
                       float* __restrict__ h, float* __restrict__ c){
  __shared__ float mf[kENC];
  int b = blockIdx.x;
  const float* mp = meanp + (size_t)b * 4 * kENC;
  for (int i = threadIdx.x; i < kENC; i += 512)
    mf[i] = (mp[i] + mp[kENC + i] + mp[2*kENC + i] + mp[3*kENC + i]) * (1.f / kN);
  __syncthreads();
  int j = threadIdx.x;
  const float* W  = blockIdx.y ? Wc : Wh;
  const float* bb = blockIdx.y ? bc : bh;
  float acc = bb[j];
  for (int k = 0; k < kENC; k++) acc = fmaf(mf[k], W[k * kDEC + j], acc);
  (blockIdx.y ? c : h)[b * kDEC + j] = acc;
}

// ---------------- gather embeddings: Xemb[t*64+b][512] ----------------
__global__ __launch_bounds__(512) void k_gather(const float* __restrict__ emb,
        const int* __restrict__ captions, unsigned short* __restrict__ Xemb){
  int m = blockIdx.x;
  int t = m >> 6, b = m & 63, d = threadIdx.x;
  Xemb[(size_t)m * kE + d] = f2b(emb[(size_t)captions[b * kT + t] * kE + d]);
}

// ------- generic 16x64-per-wave MFMA GEMM: C_bf16 = A[M][K] @ Bt[N][Kslice]^T -------
template<int K, int LDA, int LDB, int LDC>
__global__ __launch_bounds__(256) void k_gemm_nt(const unsigned short* __restrict__ A,
                                                 const unsigned short* __restrict__ Bt,
                                                 unsigned short* __restrict__ Cb){
  int w = threadIdx.x >> 6, lane = threadIdx.x & 63;
  int m0 = blockIdx.x * 64 + w * 16, n0 = blockIdx.y * 64;
  int lr = lane & 15, lk = (lane >> 4) * 8;
  f4 acc[4] = {};
  const unsigned short* Ap = A  + (size_t)(m0 + lr) * LDA + lk;
  const unsigned short* Bp = Bt + (size_t)(n0 + lr) * LDB + lk;
  #pragma unroll 4
  for (int k0 = 0; k0 < K; k0 += 32){
    bf8 a  = *(const bf8*)(Ap + k0);
    bf8 b0 = *(const bf8*)(Bp + k0);
    bf8 b1 = *(const bf8*)(Bp + (size_t)16 * LDB + k0);
    bf8 b2 = *(const bf8*)(Bp + (size_t)32 * LDB + k0);
    bf8 b3 = *(const bf8*)(Bp + (size_t)48 * LDB + k0);
    acc[0] = mfma16(a, b0, acc[0]); acc[1] = mfma16(a, b1, acc[1]);
    acc[2] = mfma16(a, b2, acc[2]); acc[3] = mfma16(a, b3, acc[3]);
  }
  asm volatile("s_nop 7\n\ts_nop 7");
  int orow = (lane >> 4) * 4;
  #pragma unroll
  for (int nt = 0; nt < 4; nt++)
    #pragma unroll
    for (int r = 0; r < 4; r++)
      Cb[(size_t)(m0 + orow + r) * LDC + n0 + nt*16 + lr] = f2b(acc[nt][r]);
}

// ------- enc_att GEMM, n-fastest grid: x = n-slice (8), y = m-block (196).
//         The 8 co-running n-blocks share each A-tile → featb streamed once. -------
__global__ __launch_bounds__(256) void k_encatt_nf(const unsigned short* __restrict__ A,
                                                   const unsigned short* __restrict__ Bt,
                                                   unsigned short* __restrict__ Cb){
  int w = threadIdx.x >> 6, lane = threadIdx.x & 63;
  int n0 = blockIdx.x * 64;
  int m0 = blockIdx.y * 64 + w * 16;
  int lr = lane & 15, lk = (lane >> 4) * 8;
  f4 acc[4] = {};
  const unsigned short* Ap = A  + (size_t)(m0 + lr) * kENC + lk;
  const unsigned short* Bp = Bt + (size_t)(n0 + lr) * kENC + lk;
  #pragma unroll 4
  for (int k0 = 0; k0 < kENC; k0 += 32){
    bf8 a  = *(const bf8*)(Ap + k0);
    bf8 b0 = *(const bf8*)(Bp + k0);
    bf8 b1 = *(const bf8*)(Bp + (size_t)16 * kENC + k0);
    bf8 b2 = *(const bf8*)(Bp + (size_t)32 * kENC + k0);
    bf8 b3 = *(const bf8*)(Bp + (size_t)48 * kENC + k0);
    acc[0] = mfma16(a, b0, acc[0]); acc[1] = mfma16(a, b1, acc[1]);
    acc[2] = mfma16(a, b2, acc[2]); acc[3] = mfma16(a, b3, acc[3]);
  }
  asm volatile("s_nop 7\n\ts_nop 7");
  int orow = (lane >> 4) * 4;
  #pragma unroll
  for (int nt = 0; nt < 4; nt++)
    #pragma unroll
    for (int r = 0; r < 4; r++)
      Cb[(size_t)(m0 + orow + r) * kATT + n0 + nt*16 + lr] = f2b(acc[nt][r]);
}

// ------- fused attention: e-pass + softmax + context chunk -------
// grid (64, 4), 256 thr. Block (b,q): computes all 196 energies (redundant ×4,
// cheap L2 re-read), softmax, then ctx dims [q*512, q*512+512).
__global__ __launch_bounds__(256) void k_att(const unsigned short* __restrict__ EA,
                     const float* __restrict__ hWdec, const float* __restrict__ attv,
                     const unsigned short* __restrict__ featb,
                     unsigned short* __restrict__ Xb, float* __restrict__ alphas, int t){
  __shared__ float al[kN];
  __shared__ float red[256];
  __shared__ float cred[4][64][8];
  int b = blockIdx.x, q = blockIdx.y, tid = threadIdx.x;
  int w = tid >> 6, lane = tid & 63;
  // e-pass: wave w owns rows [w*49, w*49+49)
  {
    float hw[8], av[8];
    const float* hp = hWdec + b * kATT + lane * 8;
    const float* ap = attv + lane * 8;
    #pragma unroll
    for (int u = 0; u < 8; u++){ hw[u] = hp[u]; av[u] = ap[u]; }
    const unsigned short* eb = EA + (size_t)b * kN * kATT;
    int rbeg = w * 49, rend = rbeg + 49;
    for (int r = rbeg; r < rend; ++r){
      u4 ev = *(const u4*)(eb + (size_t)r * kATT + lane * 8);
      float s = 0.f;
      s = fmaf(th_(bf2f((unsigned short)(ev.x & 0xffffu)) + hw[0]), av[0], s);
      s = fmaf(th_(bf2f((unsigned short)(ev.x >> 16))     + hw[1]), av[1], s);
      s = fmaf(th_(bf2f((unsigned short)(ev.y & 0xffffu)) + hw[2]), av[2], s);
      s = fmaf(th_(bf2f((unsigned short)(ev.y >> 16))     + hw[3]), av[3], s);
      s = fmaf(th_(bf2f((unsigned short)(ev.z & 0xffffu)) + hw[4]), av[4], s);
      s = fmaf(th_(bf2f((unsigned short)(ev.z >> 16))     + hw[5]), av[5], s);
      s = fmaf(th_(bf2f((unsigned short)(ev.w & 0xffffu)) + hw[6]), av[6], s);
      s = fmaf(th_(bf2f((unsigned short)(ev.w >> 16))     + hw[7]), av[7], s);
      #pragma unroll
      for (int off = 32; off; off >>= 1) s += __shfl_xor(s, off, 64);
      if (lane == 0) al[r] = s;
    }
  }
  __syncthreads();
  // softmax over al[196]
  float ev2 = (tid < kN) ? al[tid] : -1e30f;
  red[tid] = ev2; __syncthreads();
  for (int off = 128; off; off >>= 1){ if (tid < off) red[tid] = fmaxf(red[tid], red[tid + off]); __syncthreads(); }
  float mx = red[0]; __syncthreads();
  float ex = (tid < kN) ? __expf(ev2 - mx) : 0.f;
  red[tid] = ex; __syncthreads();
  for (int off = 128; off; off >>= 1){ if (tid < off) red[tid] += red[tid + off]; __syncthreads(); }
  float inv = 1.f / red[0];
  __syncthreads();
  if (tid < kN){
    float a = ex * inv;
    al[tid] = a;
    if (q == 0) alphas[((size_t)b * kTS + t) * kN + tid] = a;
  }
  __syncthreads();
  // context chunk
  int g = tid & 63, nq = tid >> 6;
  int d0 = q * 512 + g * 8;
  const unsigned short* fp = featb + (size_t)b * kN * kENC + d0;
  float c[8] = {0.f,0.f,0.f,0.f,0.f,0.f,0.f,0.f};
  int nbeg = nq * 49, nend = nbeg + 49;
  #pragma unroll 7
  for (int n = nbeg; n < nend; ++n){
    u4 v = *(const u4*)(fp + (size_t)n * kENC);
    float a = al[n];
    c[0] = fmaf(bf2f((unsigned short)(v.x & 0xffffu)), a, c[0]);
    c[1] = fmaf(bf2f((unsigned short)(v.x >> 16)),     a, c[1]);
    c[2] = fmaf(bf2f((unsigned short)(v.y & 0xffffu)), a, c[2]);
    c[3] = fmaf(bf2f((unsigned short)(v.y >> 16)),     a, c[3]);
    c[4] = fmaf(bf2f((unsigned short)(v.z & 0xffffu)), a, c[4]);
    c[5] = fmaf(bf2f((unsigned short)(v.z >> 16)),     a, c[5]);
    c[6] = fmaf(bf2f((unsigned short)(v.w & 0xffffu)), a, c[6]);
    c[7] = fmaf(bf2f((unsigned short)(v.w >> 16)),     a, c[7]);
  }
  if (nq){
    #pragma unroll
    for (int j = 0; j < 8; j++) cred[nq][g][j] = c[j];
  }
  __syncthreads();
  if (nq == 0){
    unsigned outw[4];
    #pragma unroll
    for (int j = 0; j < 4; j++){
      float lo = c[2*j]   + cred[1][g][2*j]   + cred[2][g][2*j]   + cred[3][g][2*j];
      float hi = c[2*j+1] + cred[1][g][2*j+1] + cred[2][g][2*j+1] + cred[3][g][2*j+1];
      outw[j] = ((unsigned)f2b(hi) << 16) | (unsigned)f2b(lo);
    }
    *(u4*)(Xb + (size_t)b * kKG + d0) = *(u4*)outw;
  }
}

// ---------------- per-step gates GEMM split-K over K=2560 ----------------
__global__ __launch_bounds__(256) void k_gates(const unsigned short* __restrict__ X,
        const unsigned short* __restrict__ Wih, const unsigned short* __restrict__ Whh,
        float* __restrict__ gpart){
  int w = threadIdx.x >> 6, lane = threadIdx.x & 63;
  int n0 = blockIdx.x * 64 + w * 16, ks = blockIdx.y;
  int lr = lane & 15, lk = (lane >> 4) * 8;
  int nrow = n0 + lr;
  f4 acc[4] = {};
  const unsigned short* Xp = X + (size_t)lr * kKG + ks * kKSP + lk;
  #pragma unroll 2
  for (int kt = 0; kt < kKSP; kt += 32){
    int kk = ks * kKSP + kt + lk;
    bf8 a0 = *(const bf8*)(Xp + kt);
    bf8 a1 = *(const bf8*)(Xp + 16 * kKG + kt);
    bf8 a2 = *(const bf8*)(Xp + 32 * kKG + kt);
    bf8 a3 = *(const bf8*)(Xp + 48 * kKG + kt);
    const unsigned short* bp = (kk < kENC) ? (Wih + (size_t)nrow * kKIH + kE + kk)
                                           : (Whh + (size_t)nrow * kDEC + (kk - kENC));
    bf8 b = *(const bf8*)bp;
    acc[0] = mfma16(a0, b, acc[0]); acc[1] = mfma16(a1, b, acc[1]);
    acc[2] = mfma16(a2, b, acc[2]); acc[3] = mfma16(a3, b, acc[3]);
  }
  asm volatile("s_nop 7\n\ts_nop 7");
  float* gp = gpart + (size_t)ks * kB * kG;
  int orow = (lane >> 4) * 4;
  #pragma unroll
  for (int mt = 0; mt < 4; mt++)
    #pragma unroll
    for (int r = 0; r < 4; r++)
      gp[(size_t)(mt*16 + orow + r) * kG + n0 + lr] = acc[mt][r];
}

// ---------------- LSTM pointwise + h stores + hWdec ----------------
__global__ __launch_bounds__(512) void k_lstm(const float* __restrict__ gpart,
      const unsigned short* __restrict__ Gxb,
      const float* __restrict__ bih, const float* __restrict__ bhh,
      float* __restrict__ c, unsigned short* __restrict__ Xb,
      unsigned short* __restrict__ Hall,
      const float* __restrict__ WdecT, float* __restrict__ hWdec, int t){
  __shared__ float hl[kDEC];
  int b = blockIdx.x, d = threadIdx.x;
  int m = t * kB + b;
  float gi = 0.f, gf = 0.f, gg = 0.f, go = 0.f;
  for (int ks = 0; ks < kSPL; ks++){
    const float* gp = gpart + ((size_t)ks * kB + b) * kG;
    gi += gp[d]; gf += gp[kDEC + d]; gg += gp[2*kDEC + d]; go += gp[3*kDEC + d];
  }
  const unsigned short* gx = Gxb + (size_t)m * kG;
  gi += bf2f(gx[d])          + bih[d]          + bhh[d];
  gf += bf2f(gx[kDEC + d])   + bih[kDEC + d]   + bhh[kDEC + d];
  gg += bf2f(gx[2*kDEC + d]) + bih[2*kDEC + d] + bhh[2*kDEC + d];
  go += bf2f(gx[3*kDEC + d]) + bih[3*kDEC + d] + bhh[3*kDEC + d];
  float cn = sg_(gf) * c[b*kDEC + d] + sg_(gi) * th_(gg);
  float hn = sg_(go) * th_(cn);
  c[b*kDEC + d] = cn;
  hl[d] = hn;
  unsigned short hb = f2b(hn);
  Xb[(size_t)b*kKG + kENC + d] = hb;
  Hall[((size_t)b*kTS + t)*kDEC + d] = hb;
  __syncthreads();
  const float* wr = WdecT + (size_t)d * kATT;
  float a = 0.f;
  #pragma unroll 8
  for (int kk = 0; kk < kATT; kk += 4){
    float4 wv = *(const float4*)(wr + kk);
    a = fmaf(wv.x, hl[kk + 0], a);
    a = fmaf(wv.y, hl[kk + 1], a);
    a = fmaf(wv.z, hl[kk + 2], a);
    a = fmaf(wv.w, hl[kk + 3], a);
  }
  hWdec[b * kATT + d] = a;
}

// ---------------- initial h0 -> Xb + hWdec ----------------
__global__ __launch_bounds__(512) void k_prep(const float* __restrict__ h0,
      unsigned short* __restrict__ Xb,
      const float* __restrict__ WdecT, float* __restrict__ hWdec){
  __shared__ float hl[kDEC];
  int b = blockIdx.x, d = threadIdx.x;
  float hv = h0[b*kDEC + d];
  hl[d] = hv;
  Xb[(size_t)b*kKG + kENC + d] = f2b(hv);
  __syncthreads();
  const float* wr = WdecT + (size_t)d * kATT;
  float a = 0.f;
  #pragma unroll 8
  for (int kk = 0; kk < kATT; kk += 4){
    float4 wv = *(const float4*)(wr + kk);
    a = fmaf(wv.x, hl[kk + 0], a);
    a = fmaf(wv.y, hl[kk + 1], a);
    a = fmaf(wv.z, hl[kk + 2], a);
    a = fmaf(wv.w, hl[kk + 3], a);
  }
  hWdec[b * kATT + d] = a;
}

// ---------------- batched out-projection; NT stores for preds ----------------
constexpr int kLDW = 132;   // padded LDS rows (conflict-free)
__global__ __launch_bounds__(512) void k_bigout(const unsigned short* __restrict__ Hall,
        const unsigned short* __restrict__ Wt,  // [32000][512]
        const float* __restrict__ bias, float* __restrict__ preds){
  __shared__ float st[64][kLDW];
  int w = threadIdx.x >> 6, lane = threadIdx.x & 63;
  int m0 = blockIdx.x * 256;
  int n0 = blockIdx.y * 128;
  int lr = lane & 15, lk = (lane >> 4) * 8;
  f4 acc[2][8];
  #pragma unroll
  for (int nt = 0; nt < 8; nt++){
    float bv = bias[n0 + nt*16 + lr];
    acc[0][nt] = (f4){bv, bv, bv, bv};
    acc[1][nt] = (f4){bv, bv, bv, bv};
  }
  const unsigned short* Ap = Hall + (size_t)(m0 + w*32 + lr) * kDEC + lk;
  const unsigned short* Bp = Wt + (size_t)(n0 + lr) * kDEC + lk;
  #pragma unroll 2
  for (int k0 = 0; k0 < kDEC; k0 += 32){
    bf8 a0 = *(const bf8*)(Ap + k0);
    bf8 a1 = *(const bf8*)(Ap + 16*kDEC + k0);
    #pragma unroll
    for (int nt = 0; nt < 8; nt++){
      bf8 b = *(const bf8*)(Bp + (size_t)nt*16*kDEC + k0);
      acc[0][nt] = mfma16(a0, b, acc[0][nt]);
      acc[1][nt] = mfma16(a1, b, acc[1][nt]);
    }
  }
  asm volatile("s_nop 7\n\ts_nop 7");
  int orow = (lane >> 4) * 4;
  for (int c = 0; c < 4; c++){
    __syncthreads();
    if ((w >> 1) == c){
      int rbase = (w & 1) * 32;
      #pragma unroll
      for (int half = 0; half < 2; half++)
        #pragma unroll
        for (int nt = 0; nt < 8; nt++)
          #pragma unroll
          for (int r = 0; r < 4; r++)
            st[rbase + half*16 + orow + r][nt*16 + lr] = acc[half][nt][r];
    }
    __syncthreads();
    int mbase = m0 + c*64;
    #pragma unroll
    for (int p = 0; p < 4; p++){
      int idx = threadIdx.x + p*512;
      int row = idx >> 5, c4 = idx & 31;
      int m = mbase + row;
      if (m < kM){
        f4 v = *(const f4*)(&st[row][c4*4]);
        __builtin_nontemporal_store(v, (f4*)(preds + (size_t)m * kV + n0 + c4*4));
      }
    }
  }
}

extern "C" void kernel_launch(void* const* d_in, const int* in_sizes, int n_in,
                              void* d_out, int out_size, void* d_ws, size_t ws_size,
                              hipStream_t stream) {
  const float* feat     = (const float*)d_in[0];
  const int*   captions = (const int*)  d_in[1];
  const float* emb      = (const float*)d_in[2];
  const float* attWenc  = (const float*)d_in[3];
  const float* attWdec  = (const float*)d_in[4];
  const float* attv     = (const float*)d_in[5];
  const float* ihW      = (const float*)d_in[6];
  const float* ihb      = (const float*)d_in[7];
  const float* icW      = (const float*)d_in[8];
  const float* icb      = (const float*)d_in[9];
  const float* Wih      = (const float*)d_in[10];
  const float* Whh      = (const float*)d_in[11];
  const float* bih      = (const float*)d_in[12];
  const float* bhh      = (const float*)d_in[13];
  const float* outW     = (const float*)d_in[14];
  const float* outb     = (const float*)d_in[15];

  float* preds  = (float*)d_out;                       // [64][31][32000] rows m'=b*31+t
  float* alphas = preds + (size_t)kB * kTS * kV;       // [64][31][196]

  char* p = (char*)d_ws;
  unsigned short* featb  = (unsigned short*)p; p += (size_t)kB*kN*kENC*2;   // 51.4 MB
  unsigned short* outWb  = (unsigned short*)p; p += (size_t)kV*kDEC*2;      // 32.8 MB
  unsigned short* Wihb   = (unsigned short*)p; p += (size_t)kG*kKIH*2;      // 10.5 MB
  unsigned short* Whhb   = (unsigned short*)p; p += (size_t)kG*kDEC*2;      //  2.1 MB
  unsigned short* attWT  = (unsigned short*)p; p += (size_t)kATT*kENC*2;    //  2.1 MB
  unsigned short* encattb= (unsigned short*)p; p += (size_t)kB*kN*kATT*2;   // 12.8 MB
  unsigned short* Gxb    = (unsigned short*)p; p += (size_t)kMP*kG*2;       //  8.4 MB
  unsigned short* Hall   = (unsigned short*)p; p += (size_t)kMP*kDEC*2;     //  2.1 MB
  unsigned short* Xemb   = Hall;   // dead before Hall is written
  unsigned short* Xb     = (unsigned short*)p; p += (size_t)kB*kKG*2;       //  0.33 MB
  float* WdecTf = (float*)p; p += (size_t)kATT*kDEC*4;                      //  1.0 MB fp32
  float* gpart  = (float*)p; p += (size_t)kSPL*kB*kG*4;                     //  4.2 MB
  float* meanp  = (float*)p; p += (size_t)kB*4*kENC*4;                      //  2.1 MB
  float* hbuf   = (float*)p; p += (size_t)kB*kDEC*4;
  float* cws    = (float*)p; p += (size_t)kB*kDEC*4;
  float* hWdec  = (float*)p; p += (size_t)kB*kATT*4;

  k_cvtmean<<<dim3(kB, 4), 256, 0, stream>>>(feat, featb, meanp);
  k_cvt<<<(kG*kKIH/8 + 255)/256, 256, 0, stream>>>(Wih, Wihb, kG*kKIH/8);
  k_cvt<<<(kG*kDEC/8 + 255)/256, 256, 0, stream>>>(Whh, Whhb, kG*kDEC/8);
  k_tcvt<<<dim3(kATT/32, kENC/32), 256, 0, stream>>>(attWenc, attWT, kENC, kATT);
  k_tf32<<<dim3(kATT/32, kDEC/32), 256, 0, stream>>>(attWdec, WdecTf, kDEC, kATT);
  k_tcvt<<<dim3(kV/32, kDEC/32), 256, 0, stream>>>(outW, outWb, kDEC, kV);

  k_init<<<dim3(kB, 2), 512, 0, stream>>>(meanp, ihW, ihb, icW, icb, hbuf, cws);

  // Gx[m][2048] = Xemb[m][512] @ Wih[:,0:512]^T
  k_gather<<<kM, 512, 0, stream>>>(emb, captions, Xemb);
  k_gemm_nt<kE, kE, kKIH, kG><<<dim3(kMP/64, kG/64), 256, 0, stream>>>(Xemb, Wihb, Gxb);

  // enc_att = featb @ attWT^T  (n-fastest grid for A-stream sharing)
  k_encatt_nf<<<dim3(kATT/64, kB*kN/64), 256, 0, stream>>>(featb, attWT, encattb);

  k_prep<<<kB, 512, 0, stream>>>(hbuf, Xb, WdecTf, hWdec);

  for (int t = 0; t < kTS; ++t) {
    k_att<<<dim3(kB, 4), 256, 0, stream>>>(encattb, hWdec, attv, featb, Xb, alphas, t);
    k_gates<<<dim3(kG/64, kSPL), 256, 0, stream>>>(Xb, Wihb, Whhb, gpart);
    k_lstm<<<kB, 512, 0, stream>>>(gpart, Gxb, bih, bhh, cws, Xb, Hall,
                                   WdecTf, hWdec, t);
  }

  k_bigout<<<dim3(kMP/256, kV/128), 512, 0, stream>>>(Hall, outWb, outb, preds);
}

// Round 13
// 2784.738 us; speedup vs baseline: 1.1608x; 1.1608x over previous
//
#include <hip/hip_runtime.h>
#include <math.h>

constexpr int kB = 64, kN = 196, kENC = 2048, kDEC = 512, kE = 512, kATT = 512;
constexpr int kV = 32000, kT = 32, kTS = 31;
constexpr int kKIH = kE + kENC;        // 2560 (W_ih K)
constexpr int kKG  = kENC + kDEC;      // 2560 (per-step gates K: [ctx; h])
constexpr int kG   = 4 * kDEC;         // 2048
constexpr int kSPL = 8, kKSP = kKG / kSPL; // 320
constexpr int kM   = kTS * kB;         // 1984
constexpr int kMP  = 2048;

typedef __attribute__((ext_vector_type(8))) short bf8;
typedef __attribute__((ext_vector_type(4))) float f4;
typedef __attribute__((ext_vector_type(4))) unsigned u4;

__device__ __forceinline__ f4 mfma16(bf8 a, bf8 b, f4 c){
  asm("v_mfma_f32_16x16x32_bf16 %0, %1, %2, %0" : "+v"(c) : "v"(a), "v"(b));
  return c;
}
__device__ __forceinline__ float bf2f(unsigned short u){
  return __uint_as_float(((unsigned)u) << 16);
}
__device__ __forceinline__ unsigned short f2b(float f){
  unsigned u = __float_as_uint(f);
  u += 0x7fffu + ((u >> 16) & 1u);
  return (unsigned short)(u >> 16);
}
__device__ __forceinline__ float th_(float x){
  float e2 = __expf(2.f * x);
  return 1.f - 2.f * __builtin_amdgcn_rcpf(e2 + 1.f);
}
__device__ __forceinline__ float sg_(float x){
  return __builtin_amdgcn_rcpf(1.f + __expf(-x));
}
__device__ __forceinline__ float erow_(u4 v, const float* hw, const float* av){
  float s = 0.f;
  s = fmaf(th_(bf2f((unsigned short)(v.x & 0xffffu)) + hw[0]), av[0], s);
  s = fmaf(th_(bf2f((unsigned short)(v.x >> 16))     + hw[1]), av[1], s);
  s = fmaf(th_(bf2f((unsigned short)(v.y & 0xffffu)) + hw[2]), av[2], s);
  s = fmaf(th_(bf2f((unsigned short)(v.y >> 16))     + hw[3]), av[3], s);
  s = fmaf(th_(bf2f((unsigned short)(v.z & 0xffffu)) + hw[4]), av[4], s);
  s = fmaf(th_(bf2f((unsigned short)(v.z >> 16))     + hw[5]), av[5], s);
  s = fmaf(th_(bf2f((unsigned short)(v.w & 0xffffu)) + hw[6]), av[6], s);
  s = fmaf(th_(bf2f((unsigned short)(v.w >> 16))     + hw[7]), av[7], s);
  return s;
}

// ---------------- fp32 -> bf16 bulk convert ----------------
__global__ void k_cvt(const float* __restrict__ src, unsigned short* __restrict__ dst, int n8){
  int i = blockIdx.x * 256 + threadIdx.x;
  if (i >= n8) return;
  float4 a = ((const float4*)src)[2 * i];
  float4 b = ((const float4*)src)[2 * i + 1];
  union { unsigned short u[8]; uint4 v; } t;
  t.u[0] = f2b(a.x); t.u[1] = f2b(a.y); t.u[2] = f2b(a.z); t.u[3] = f2b(a.w);
  t.u[4] = f2b(b.x); t.u[5] = f2b(b.y); t.u[6] = f2b(b.z); t.u[7] = f2b(b.w);
  ((uint4*)dst)[i] = t.v;
}

// ------- features: fp32->bf16 convert + partial mean over n (fused) -------
__global__ __launch_bounds__(256) void k_cvtmean(const float* __restrict__ feat,
        unsigned short* __restrict__ featb, float* __restrict__ meanp){
  int b = blockIdx.x, nq = blockIdx.y, tid = threadIdx.x;
  int d0 = tid * 8;
  const float* fp = feat + (size_t)b * kN * kENC + d0;
  unsigned short* op = featb + (size_t)b * kN * kENC + d0;
  float s[8] = {0.f,0.f,0.f,0.f,0.f,0.f,0.f,0.f};
  int nbeg = nq * 49, nend = nbeg + 49;
  #pragma unroll 4
  for (int n = nbeg; n < nend; ++n){
    float4 a = *(const float4*)(fp + (size_t)n * kENC);
    float4 c = *(const float4*)(fp + (size_t)n * kENC + 4);
    union { unsigned short u[8]; u4 v; } t;
    t.u[0] = f2b(a.x); t.u[1] = f2b(a.y); t.u[2] = f2b(a.z); t.u[3] = f2b(a.w);
    t.u[4] = f2b(c.x); t.u[5] = f2b(c.y); t.u[6] = f2b(c.z); t.u[7] = f2b(c.w);
    *(u4*)(op + (size_t)n * kENC) = t.v;
    s[0] += a.x; s[1] += a.y; s[2] += a.z; s[3] += a.w;
    s[4] += c.x; s[5] += c.y; s[6] += c.z; s[7] += c.w;
  }
  float* mp = meanp + ((size_t)b * 4 + nq) * kENC + d0;
  #pragma unroll
  for (int j = 0; j < 8; j++) mp[j] = s[j];
}

// ---------------- fp32 [R][C] -> bf16 [C][R] ----------------
__global__ __launch_bounds__(256) void k_tcvt(const float* __restrict__ src,
                                              unsigned short* __restrict__ dst, int R, int C){
  __shared__ float t[32][33];
  int c0 = blockIdx.x * 32, r0 = blockIdx.y * 32;
  int tx = threadIdx.x & 31, ty = threadIdx.x >> 5;
  #pragma unroll
  for (int j = 0; j < 4; j++)
    t[ty + 8*j][tx] = src[(size_t)(r0 + ty + 8*j) * C + c0 + tx];
  __syncthreads();
  #pragma unroll
  for (int j = 0; j < 4; j++)
    dst[(size_t)(c0 + ty + 8*j) * R + r0 + tx] = f2b(t[tx][ty + 8*j]);
}

// ---------------- fp32 [R][C] -> fp32 [C][R] ----------------
__global__ __launch_bounds__(256) void k_tf32(const float* __restrict__ src,
                                              float* __restrict__ dst, int R, int C){
  __shared__ float t[32][33];
  int c0 = blockIdx.x * 32, r0 = blockIdx.y * 32;
  int tx = threadIdx.x & 31, ty = threadIdx.x >> 5;
  #pragma unroll
  for (int j = 0; j < 4; j++)
    t[ty + 8*j][tx] = src[(size_t)(r0 + ty + 8*j) * C + c0 + tx];
  __syncthreads();
  #pragma unroll
  for (int j = 0; j < 4; j++)
    dst[(size_t)(c0 + ty + 8*j) * R + r0 + tx] = t[tx][ty + 8*j];
}

// ---------------- h0 / c0 (sums 4 mean partials) ----------------
__global__ __launch_bounds__(512) void k_init(const float* __restrict__ meanp,
                       const float* __restrict__ Wh, const float* __restrict__ bh,
                       const float* __restrict__ Wc, const float* __restrict__ bc,
                       float* __restrict__ h, float* __restrict__ c){
  __shared__ float mf[kENC];
  int b = blockIdx.x;
  const float* mp = meanp + (size_t)b * 4 * kENC;
  for (int i = threadIdx.x; i < kENC; i += 512)
    mf[i] = (mp[i] + mp[kENC + i] + mp[2*kENC + i] + mp[3*kENC + i]) * (1.f / kN);
  __syncthreads();
  int j = threadIdx.x;
  const float* W  = blockIdx.y ? Wc : Wh;
  const float* bb = blockIdx.y ? bc : bh;
  float acc = bb[j];
  for (int k = 0; k < kENC; k++) acc = fmaf(mf[k], W[k * kDEC + j], acc);
  (blockIdx.y ? c : h)[b * kDEC + j] = acc;
}

// ---------------- gather embeddings: Xemb[t*64+b][512] ----------------
__global__ __launch_bounds__(512) void k_gather(const float* __restrict__ emb,
        const int* __restrict__ captions, unsigned short* __restrict__ Xemb){
  int m = blockIdx.x;
  int t = m >> 6, b = m & 63, d = threadIdx.x;
  Xemb[(size_t)m * kE + d] = f2b(emb[(size_t)captions[b * kT + t] * kE + d]);
}

// ------- generic 16x64-per-wave MFMA GEMM: C_bf16 = A[M][K] @ Bt[N][Kslice]^T -------
template<int K, int LDA, int LDB, int LDC>
__global__ __launch_bounds__(256) void k_gemm_nt(const unsigned short* __restrict__ A,
                                                 const unsigned short* __restrict__ Bt,
                                                 unsigned short* __restrict__ Cb){
  int w = threadIdx.x >> 6, lane = threadIdx.x & 63;
  int m0 = blockIdx.x * 64 + w * 16, n0 = blockIdx.y * 64;
  int lr = lane & 15, lk = (lane >> 4) * 8;
  f4 acc[4] = {};
  const unsigned short* Ap = A  + (size_t)(m0 + lr) * LDA + lk;
  const unsigned short* Bp = Bt + (size_t)(n0 + lr) * LDB + lk;
  #pragma unroll 4
  for (int k0 = 0; k0 < K; k0 += 32){
    bf8 a  = *(const bf8*)(Ap + k0);
    bf8 b0 = *(const bf8*)(Bp + k0);
    bf8 b1 = *(const bf8*)(Bp + (size_t)16 * LDB + k0);
    bf8 b2 = *(const bf8*)(Bp + (size_t)32 * LDB + k0);
    bf8 b3 = *(const bf8*)(Bp + (size_t)48 * LDB + k0);
    acc[0] = mfma16(a, b0, acc[0]); acc[1] = mfma16(a, b1, acc[1]);
    acc[2] = mfma16(a, b2, acc[2]); acc[3] = mfma16(a, b3, acc[3]);
  }
  asm volatile("s_nop 7\n\ts_nop 7");
  int orow = (lane >> 4) * 4;
  #pragma unroll
  for (int nt = 0; nt < 4; nt++)
    #pragma unroll
    for (int r = 0; r < 4; r++)
      Cb[(size_t)(m0 + orow + r) * LDC + n0 + nt*16 + lr] = f2b(acc[nt][r]);
}

// ---------------- softmax (redundant per block) + context chunk ----------------
__global__ __launch_bounds__(256) void k_ctx(const float* __restrict__ e,
                     const unsigned short* __restrict__ featb,
                     unsigned short* __restrict__ Xb, float* __restrict__ alphas, int t){
  __shared__ float al[kN];
  __shared__ float red[256];
  __shared__ float cred[4][64][8];
  int b = blockIdx.x, q = blockIdx.y, tid = threadIdx.x;
  float ev = (tid < kN) ? e[b * kN + tid] : -1e30f;
  red[tid] = ev; __syncthreads();
  for (int off = 128; off; off >>= 1){ if (tid < off) red[tid] = fmaxf(red[tid], red[tid + off]); __syncthreads(); }
  float mx = red[0]; __syncthreads();
  float ex = (tid < kN) ? __expf(ev - mx) : 0.f;
  red[tid] = ex; __syncthreads();
  for (int off = 128; off; off >>= 1){ if (tid < off) red[tid] += red[tid + off]; __syncthreads(); }
  float inv = 1.f / red[0];
  if (tid < kN){
    float a = ex * inv;
    al[tid] = a;
    if (q == 0) alphas[((size_t)b * kTS + t) * kN + tid] = a;
  }
  __syncthreads();
  int g = tid & 63, nq = tid >> 6;
  int d0 = q * 512 + g * 8;
  const unsigned short* fp = featb + (size_t)b * kN * kENC + d0;
  float c[8] = {0.f,0.f,0.f,0.f,0.f,0.f,0.f,0.f};
  int nbeg = nq * 49, nend = nbeg + 49;
  #pragma unroll 7
  for (int n = nbeg; n < nend; ++n){
    u4 v = *(const u4*)(fp + (size_t)n * kENC);
    float a = al[n];
    c[0] = fmaf(bf2f((unsigned short)(v.x & 0xffffu)), a, c[0]);
    c[1] = fmaf(bf2f((unsigned short)(v.x >> 16)),     a, c[1]);
    c[2] = fmaf(bf2f((unsigned short)(v.y & 0xffffu)), a, c[2]);
    c[3] = fmaf(bf2f((unsigned short)(v.y >> 16)),     a, c[3]);
    c[4] = fmaf(bf2f((unsigned short)(v.z & 0xffffu)), a, c[4]);
    c[5] = fmaf(bf2f((unsigned short)(v.z >> 16)),     a, c[5]);
    c[6] = fmaf(bf2f((unsigned short)(v.w & 0xffffu)), a, c[6]);
    c[7] = fmaf(bf2f((unsigned short)(v.w >> 16)),     a, c[7]);
  }
  if (nq){
    #pragma unroll
    for (int j = 0; j < 8; j++) cred[nq][g][j] = c[j];
  }
  __syncthreads();
  if (nq == 0){
    unsigned outw[4];
    #pragma unroll
    for (int j = 0; j < 4; j++){
      float lo = c[2*j]   + cred[1][g][2*j]   + cred[2][g][2*j]   + cred[3][g][2*j];
      float hi = c[2*j+1] + cred[1][g][2*j+1] + cred[2][g][2*j+1] + cred[3][g][2*j+1];
      outw[j] = ((unsigned)f2b(hi) << 16) | (unsigned)f2b(lo);
    }
    *(u4*)(Xb + (size_t)b * kKG + d0) = *(u4*)outw;
  }
}

// ---------------- per-step gates GEMM split-K over K=2560 ----------------
__global__ __launch_bounds__(256) void k_gates(const unsigned short* __restrict__ X,
        const unsigned short* __restrict__ Wih, const unsigned short* __restrict__ Whh,
        float* __restrict__ gpart){
  int w = threadIdx.x >> 6, lane = threadIdx.x & 63;
  int n0 = blockIdx.x * 64 + w * 16, ks = blockIdx.y;
  int lr = lane & 15, lk = (lane >> 4) * 8;
  int nrow = n0 + lr;
  f4 acc[4] = {};
  const unsigned short* Xp = X + (size_t)lr * kKG + ks * kKSP + lk;
  #pragma unroll 2
  for (int kt = 0; kt < kKSP; kt += 32){
    int kk = ks * kKSP + kt + lk;
    bf8 a0 = *(const bf8*)(Xp + kt);
    bf8 a1 = *(const bf8*)(Xp + 16 * kKG + kt);
    bf8 a2 = *(const bf8*)(Xp + 32 * kKG + kt);
    bf8 a3 = *(const bf8*)(Xp + 48 * kKG + kt);
    const unsigned short* bp = (kk < kENC) ? (Wih + (size_t)nrow * kKIH + kE + kk)
                                           : (Whh + (size_t)nrow * kDEC + (kk - kENC));
    bf8 b = *(const bf8*)bp;
    acc[0] = mfma16(a0, b, acc[0]); acc[1] = mfma16(a1, b, acc[1]);
    acc[2] = mfma16(a2, b, acc[2]); acc[3] = mfma16(a3, b, acc[3]);
  }
  asm volatile("s_nop 7\n\ts_nop 7");
  float* gp = gpart + (size_t)ks * kB * kG;
  int orow = (lane >> 4) * 4;
  #pragma unroll
  for (int mt = 0; mt < 4; mt++)
    #pragma unroll
    for (int r = 0; r < 4; r++)
      gp[(size_t)(mt*16 + orow + r) * kG + n0 + lr] = acc[mt][r];
}

// ------- LSTM pointwise + h stores + hWdec + NEXT-STEP e-pass (fused) -------
__global__ __launch_bounds__(512) void k_lstm(const float* __restrict__ gpart,
      const unsigned short* __restrict__ Gxb,
      const float* __restrict__ bih, const float* __restrict__ bhh,
      float* __restrict__ c, unsigned short* __restrict__ Xb,
      unsigned short* __restrict__ Hall,
      const float* __restrict__ WdecT,
      const unsigned short* __restrict__ EA, const float* __restrict__ attv,
      float* __restrict__ evec, int t){
  __shared__ float hl[kDEC];
  __shared__ float hwl[kATT];
  int b = blockIdx.x, d = threadIdx.x;
  int m = t * kB + b;
  float gi = 0.f, gf = 0.f, gg = 0.f, go = 0.f;
  for (int ks = 0; ks < kSPL; ks++){
    const float* gp = gpart + ((size_t)ks * kB + b) * kG;
    gi += gp[d]; gf += gp[kDEC + d]; gg += gp[2*kDEC + d]; go += gp[3*kDEC + d];
  }
  const unsigned short* gx = Gxb + (size_t)m * kG;
  gi += bf2f(gx[d])          + bih[d]          + bhh[d];
  gf += bf2f(gx[kDEC + d])   + bih[kDEC + d]   + bhh[kDEC + d];
  gg += bf2f(gx[2*kDEC + d]) + bih[2*kDEC + d] + bhh[2*kDEC + d];
  go += bf2f(gx[3*kDEC + d]) + bih[3*kDEC + d] + bhh[3*kDEC + d];
  float cn = sg_(gf) * c[b*kDEC + d] + sg_(gi) * th_(gg);
  float hn = sg_(go) * th_(cn);
  c[b*kDEC + d] = cn;
  hl[d] = hn;
  unsigned short hb = f2b(hn);
  Xb[(size_t)b*kKG + kENC + d] = hb;
  Hall[((size_t)b*kTS + t)*kDEC + d] = hb;
  __syncthreads();
  // hWdec[j] for j = d (fp32 weights, L2-resident)
  {
    const float* wr = WdecT + (size_t)d * kATT;
    float a = 0.f;
    #pragma unroll 8
    for (int kk = 0; kk < kATT; kk += 4){
      float4 wv = *(const float4*)(wr + kk);
      a = fmaf(wv.x, hl[kk + 0], a);
      a = fmaf(wv.y, hl[kk + 1], a);
      a = fmaf(wv.z, hl[kk + 2], a);
      a = fmaf(wv.w, hl[kk + 3], a);
    }
    hwl[d] = a;
  }
  __syncthreads();
  // e-pass for next step (2-row pipeline per wave) -> evec
  int w = d >> 6, lane = d & 63;
  float hw[8], av[8];
  #pragma unroll
  for (int u = 0; u < 8; u++){ hw[u] = hwl[lane*8 + u]; av[u] = attv[lane*8 + u]; }
  const unsigned short* eb = EA + (size_t)b * kN * kATT;
  for (int r0 = w; r0 < kN; r0 += 16){
    int r1 = r0 + 8;
    u4 e0 = *(const u4*)(eb + (size_t)r0 * kATT + lane*8);
    u4 e1 = (r1 < kN) ? *(const u4*)(eb + (size_t)r1 * kATT + lane*8) : e0;
    float s0 = erow_(e0, hw, av);
    float s1 = erow_(e1, hw, av);
    #pragma unroll
    for (int off = 32; off; off >>= 1){
      s0 += __shfl_xor(s0, off, 64);
      s1 += __shfl_xor(s1, off, 64);
    }
    if (lane == 0){
      evec[b*kN + r0] = s0;
      if (r1 < kN) evec[b*kN + r1] = s1;
    }
  }
}

// ---------------- initial h0 -> Xb + e-pass for t=0 ----------------
__global__ __launch_bounds__(512) void k_prep(const float* __restrict__ h0,
      unsigned short* __restrict__ Xb,
      const float* __restrict__ WdecT,
      const unsigned short* __restrict__ EA, const float* __restrict__ attv,
      float* __restrict__ evec){
  __shared__ float hl[kDEC];
  __shared__ float hwl[kATT];
  int b = blockIdx.x, d = threadIdx.x;
  float hv = h0[b*kDEC + d];
  hl[d] = hv;
  Xb[(size_t)b*kKG + kENC + d] = f2b(hv);
  __syncthreads();
  {
    const float* wr = WdecT + (size_t)d * kATT;
    float a = 0.f;
    #pragma unroll 8
    for (int kk = 0; kk < kATT; kk += 4){
      float4 wv = *(const float4*)(wr + kk);
      a = fmaf(wv.x, hl[kk + 0], a);
      a = fmaf(wv.y, hl[kk + 1], a);
      a = fmaf(wv.z, hl[kk + 2], a);
      a = fmaf(wv.w, hl[kk + 3], a);
    }
    hwl[d] = a;
  }
  __syncthreads();
  int w = d >> 6, lane = d & 63;
  float hw[8], av[8];
  #pragma unroll
  for (int u = 0; u < 8; u++){ hw[u] = hwl[lane*8 + u]; av[u] = attv[lane*8 + u]; }
  const unsigned short* eb = EA + (size_t)b * kN * kATT;
  for (int r0 = w; r0 < kN; r0 += 16){
    int r1 = r0 + 8;
    u4 e0 = *(const u4*)(eb + (size_t)r0 * kATT + lane*8);
    u4 e1 = (r1 < kN) ? *(const u4*)(eb + (size_t)r1 * kATT + lane*8) : e0;
    float s0 = erow_(e0, hw, av);
    float s1 = erow_(e1, hw, av);
    #pragma unroll
    for (int off = 32; off; off >>= 1){
      s0 += __shfl_xor(s0, off, 64);
      s1 += __shfl_xor(s1, off, 64);
    }
    if (lane == 0){
      evec[b*kN + r0] = s0;
      if (r1 < kN) evec[b*kN + r1] = s1;
    }
  }
}

// ---------------- batched out-projection (r11-proven form) ----------------
constexpr int kLDW = 132;   // padded LDS rows (conflict-free)
__global__ __launch_bounds__(512) void k_bigout(const unsigned short* __restrict__ Hall,
        const unsigned short* __restrict__ Wt,  // [32000][512]
        const float* __restrict__ bias, float* __restrict__ preds){
  __shared__ float st[64][kLDW];
  int w = threadIdx.x >> 6, lane = threadIdx.x & 63;
  int m0 = blockIdx.x * 256;
  int n0 = blockIdx.y * 128;
  int lr = lane & 15, lk = (lane >> 4) * 8;
  f4 acc[2][8];
  #pragma unroll
  for (int nt = 0; nt < 8; nt++){
    float bv = bias[n0 + nt*16 + lr];
    acc[0][nt] = (f4){bv, bv, bv, bv};
    acc[1][nt] = (f4){bv, bv, bv, bv};
  }
  const unsigned short* Ap = Hall + (size_t)(m0 + w*32 + lr) * kDEC + lk;
  const unsigned short* Bp = Wt + (size_t)(n0 + lr) * kDEC + lk;
  #pragma unroll 2
  for (int k0 = 0; k0 < kDEC; k0 += 32){
    bf8 a0 = *(const bf8*)(Ap + k0);
    bf8 a1 = *(const bf8*)(Ap + 16*kDEC + k0);
    #pragma unroll
    for (int nt = 0; nt < 8; nt++){
      bf8 b = *(const bf8*)(Bp + (size_t)nt*16*kDEC + k0);
      acc[0][nt] = mfma16(a0, b, acc[0][nt]);
      acc[1][nt] = mfma16(a1, b, acc[1][nt]);
    }
  }
  asm volatile("s_nop 7\n\ts_nop 7");
  int orow = (lane >> 4) * 4;
  for (int c = 0; c < 4; c++){
    __syncthreads();
    if ((w >> 1) == c){
      int rbase = (w & 1) * 32;
      #pragma unroll
      for (int half = 0; half < 2; half++)
        #pragma unroll
        for (int nt = 0; nt < 8; nt++)
          #pragma unroll
          for (int r = 0; r < 4; r++)
            st[rbase + half*16 + orow + r][nt*16 + lr] = acc[half][nt][r];
    }
    __syncthreads();
    int mbase = m0 + c*64;
    #pragma unroll
    for (int p = 0; p < 4; p++){
      int idx = threadIdx.x + p*512;
      int row = idx >> 5, c4 = idx & 31;
      int m = mbase + row;
      if (m < kM){
        float4 v = *(const float4*)(&st[row][c4*4]);
        *(float4*)(preds + (size_t)m * kV + n0 + c4*4) = v;
      }
    }
  }
}

extern "C" void kernel_launch(void* const* d_in, const int* in_sizes, int n_in,
                              void* d_out, int out_size, void* d_ws, size_t ws_size,
                              hipStream_t stream) {
  const float* feat     = (const float*)d_in[0];
  const int*   captions = (const int*)  d_in[1];
  const float* emb      = (const float*)d_in[2];
  const float* attWenc  = (const float*)d_in[3];
  const float* attWdec  = (const float*)d_in[4];
  const float* attv     = (const float*)d_in[5];
  const float* ihW      = (const float*)d_in[6];
  const float* ihb      = (const float*)d_in[7];
  const float* icW      = (const float*)d_in[8];
  const float* icb      = (const float*)d_in[9];
  const float* Wih      = (const float*)d_in[10];
  const float* Whh      = (const float*)d_in[11];
  const float* bih      = (const float*)d_in[12];
  const float* bhh      = (const float*)d_in[13];
  const float* outW     = (const float*)d_in[14];
  const float* outb     = (const float*)d_in[15];

  float* preds  = (float*)d_out;                       // [64][31][32000] rows m'=b*31+t
  float* alphas = preds + (size_t)kB * kTS * kV;       // [64][31][196]

  char* p = (char*)d_ws;
  unsigned short* featb  = (unsigned short*)p; p += (size_t)kB*kN*kENC*2;   // 51.4 MB
  unsigned short* outWb  = (unsigned short*)p; p += (size_t)kV*kDEC*2;      // 32.8 MB
  unsigned short* Wihb   = (unsigned short*)p; p += (size_t)kG*kKIH*2;      // 10.5 MB
  unsigned short* Whhb   = (unsigned short*)p; p += (size_t)kG*kDEC*2;      //  2.1 MB
  unsigned short* attWT  = (unsigned short*)p; p += (size_t)kATT*kENC*2;    //  2.1 MB
  unsigned short* encattb= (unsigned short*)p; p += (size_t)kB*kN*kATT*2;   // 12.8 MB
  unsigned short* Gxb    = (unsigned short*)p; p += (size_t)kMP*kG*2;       //  8.4 MB
  unsigned short* Hall   = (unsigned short*)p; p += (size_t)kMP*kDEC*2;     //  2.1 MB
  unsigned short* Xemb   = Hall;   // dead before Hall is written
  unsigned short* Xb     = (unsigned short*)p; p += (size_t)kB*kKG*2;       //  0.33 MB
  float* WdecTf = (float*)p; p += (size_t)kATT*kDEC*4;                      //  1.0 MB fp32
  float* gpart  = (float*)p; p += (size_t)kSPL*kB*kG*4;                     //  4.2 MB
  float* meanp  = (float*)p; p += (size_t)kB*4*kENC*4;                      //  2.1 MB
  float* hbuf   = (float*)p; p += (size_t)kB*kDEC*4;
  float* cws    = (float*)p; p += (size_t)kB*kDEC*4;
  float* evec   = (float*)p; p += (size_t)kB*kN*4;

  k_cvtmean<<<dim3(kB, 4), 256, 0, stream>>>(feat, featb, meanp);
  k_cvt<<<(kG*kKIH/8 + 255)/256, 256, 0, stream>>>(Wih, Wihb, kG*kKIH/8);
  k_cvt<<<(kG*kDEC/8 + 255)/256, 256, 0, stream>>>(Whh, Whhb, kG*kDEC/8);
  k_tcvt<<<dim3(kATT/32, kENC/32), 256, 0, stream>>>(attWenc, attWT, kENC, kATT);
  k_tf32<<<dim3(kATT/32, kDEC/32), 256, 0, stream>>>(attWdec, WdecTf, kDEC, kATT);
  k_tcvt<<<dim3(kV/32, kDEC/32), 256, 0, stream>>>(outW, outWb, kDEC, kV);

  k_init<<<dim3(kB, 2), 512, 0, stream>>>(meanp, ihW, ihb, icW, icb, hbuf, cws);

  // Gx[m][2048] = Xemb[m][512] @ Wih[:,0:512]^T
  k_gather<<<kM, 512, 0, stream>>>(emb, captions, Xemb);
  k_gemm_nt<kE, kE, kKIH, kG><<<dim3(kMP/64, kG/64), 256, 0, stream>>>(Xemb, Wihb, Gxb);

  // enc_att = featb @ attWT^T  (r9/r11-proven form)
  k_gemm_nt<kENC, kENC, kENC, kATT><<<dim3(kB*kN/64, kATT/64), 256, 0, stream>>>(featb, attWT, encattb);

  k_prep<<<kB, 512, 0, stream>>>(hbuf, Xb, WdecTf, encattb, attv, evec);

  for (int t = 0; t < kTS; ++t) {
    k_ctx<<<dim3(kB, 4), 256, 0, stream>>>(evec, featb, Xb, alphas, t);
    k_gates<<<dim3(kG/64, kSPL), 256, 0, stream>>>(Xb, Wihb, Whhb, gpart);
    k_lstm<<<kB, 512, 0, stream>>>(gpart, Gxb, bih, bhh, cws, Xb, Hall,
                                   WdecTf, encattb, attv, evec, t);
  }

  k_bigout<<<dim3(kMP/256, kV/128), 512, 0, stream>>>(Hall, outWb, outb, preds);
}

// Round 14
// 2329.463 us; speedup vs baseline: 1.3877x; 1.1954x over previous
//
#include <hip/hip_runtime.h>
#include <math.h>

constexpr int kB = 64, kN = 196, kENC = 2048, kDEC = 512, kE = 512, kATT = 512;
constexpr int kV = 32000, kT = 32, kTS = 31;
constexpr int kKIH = kE + kENC;        // 2560 (W_ih K)
constexpr int kKG  = kENC + kDEC;      // 2560 (per-step gates K: [ctx; h])
constexpr int kG   = 4 * kDEC;         // 2048
constexpr int kSPL = 8, kKSP = kKG / kSPL; // 320
constexpr int kM   = kTS * kB;         // 1984
constexpr int kMP  = 2048;

typedef __attribute__((ext_vector_type(8))) short bf8;
typedef __attribute__((ext_vector_type(4))) float f4;
typedef __attribute__((ext_vector_type(4))) unsigned u4;

__device__ __forceinline__ f4 mfma16(bf8 a, bf8 b, f4 c){
  asm("v_mfma_f32_16x16x32_bf16 %0, %1, %2, %0" : "+v"(c) : "v"(a), "v"(b));
  return c;
}
__device__ __forceinline__ float bf2f(unsigned short u){
  return __uint_as_float(((unsigned)u) << 16);
}
__device__ __forceinline__ unsigned short f2b(float f){
  unsigned u = __float_as_uint(f);
  u += 0x7fffu + ((u >> 16) & 1u);
  return (unsigned short)(u >> 16);
}
__device__ __forceinline__ float th_(float x){
  float e2 = __expf(2.f * x);
  return 1.f - 2.f * __builtin_amdgcn_rcpf(e2 + 1.f);
}
__device__ __forceinline__ float sg_(float x){
  return __builtin_amdgcn_rcpf(1.f + __expf(-x));
}

// ---------------- fp32 -> bf16 bulk convert ----------------
__global__ void k_cvt(const float* __restrict__ src, unsigned short* __restrict__ dst, int n8){
  int i = blockIdx.x * 256 + threadIdx.x;
  if (i >= n8) return;
  float4 a = ((const float4*)src)[2 * i];
  float4 b = ((const float4*)src)[2 * i + 1];
  union { unsigned short u[8]; uint4 v; } t;
  t.u[0] = f2b(a.x); t.u[1] = f2b(a.y); t.u[2] = f2b(a.z); t.u[3] = f2b(a.w);
  t.u[4] = f2b(b.x); t.u[5] = f2b(b.y); t.u[6] = f2b(b.z); t.u[7] = f2b(b.w);
  ((uint4*)dst)[i] = t.v;
}

// ------- features: fp32->bf16 convert + partial mean over n (fused) -------
__global__ __launch_bounds__(256) void k_cvtmean(const float* __restrict__ feat,
        unsigned short* __restrict__ featb, float* __restrict__ meanp){
  int b = blockIdx.x, nq = blockIdx.y, tid = threadIdx.x;
  int d0 = tid * 8;
  const float* fp = feat + (size_t)b * kN * kENC + d0;
  unsigned short* op = featb + (size_t)b * kN * kENC + d0;
  float s[8] = {0.f,0.f,0.f,0.f,0.f,0.f,0.f,0.f};
  int nbeg = nq * 49, nend = nbeg + 49;
  #pragma unroll 4
  for (int n = nbeg; n < nend; ++n){
    float4 a = *(const float4*)(fp + (size_t)n * kENC);
    float4 c = *(const float4*)(fp + (size_t)n * kENC + 4);
    union { unsigned short u[8]; u4 v; } t;
    t.u[0] = f2b(a.x); t.u[1] = f2b(a.y); t.u[2] = f2b(a.z); t.u[3] = f2b(a.w);
    t.u[4] = f2b(c.x); t.u[5] = f2b(c.y); t.u[6] = f2b(c.z); t.u[7] = f2b(c.w);
    *(u4*)(op + (size_t)n * kENC) = t.v;
    s[0] += a.x; s[1] += a.y; s[2] += a.z; s[3] += a.w;
    s[4] += c.x; s[5] += c.y; s[6] += c.z; s[7] += c.w;
  }
  float* mp = meanp + ((size_t)b * 4 + nq) * kENC + d0;
  #pragma unroll
  for (int j = 0; j < 8; j++) mp[j] = s[j];
}

// ---------------- fp32 [R][C] -> bf16 [C][R] ----------------
__global__ __launch_bounds__(256) void k_tcvt(const float* __restrict__ src,
                                              unsigned short* __restrict__ dst, int R, int C){
  __shared__ float t[32][33];
  int c0 = blockIdx.x * 32, r0 = blockIdx.y * 32;
  int tx = threadIdx.x & 31, ty = threadIdx.x >> 5;
  #pragma unroll
  for (int j = 0; j < 4; j++)
    t[ty + 8*j][tx] = src[(size_t)(r0 + ty + 8*j) * C + c0 + tx];
  __syncthreads();
  #pragma unroll
  for (int j = 0; j < 4; j++)
    dst[(size_t)(c0 + ty + 8*j) * R + r0 + tx] = f2b(t[tx][ty + 8*j]);
}

// ---------------- fp32 [R][C] -> fp32 [C][R] ----------------
__global__ __launch_bounds__(256) void k_tf32(const float* __restrict__ src,
                                              float* __restrict__ dst, int R, int C){
  __shared__ float t[32][33];
  int c0 = blockIdx.x * 32, r0 = blockIdx.y * 32;
  int tx = threadIdx.x & 31, ty = threadIdx.x >> 5;
  #pragma unroll
  for (int j = 0; j < 4; j++)
    t[ty + 8*j][tx] = src[(size_t)(r0 + ty + 8*j) * C + c0 + tx];
  __syncthreads();
  #pragma unroll
  for (int j = 0; j < 4; j++)
    dst[(size_t)(c0 + ty + 8*j) * R + r0 + tx] = t[tx][ty + 8*j];
}

// ---------------- h0 / c0 (sums 4 mean partials) ----------------
__global__ __launch_bounds__(512) void k_init(const float* __restrict__ meanp,
                       const float* __restrict__ Wh, const float* __restrict__ bh,
                       const float* __restrict__ Wc, const float* __restrict__ bc,
                       float* __restrict__ h, float* __restrict__ c){
  __shared__ float mf[kENC];
  int b = blockIdx.x;
  const float* mp = meanp + (size_t)b * 4 * kENC;
  for (int i = threadIdx.x; i < kENC; i += 512)
    mf[i] = (mp[i] + mp[kENC + i] + mp[2*kENC + i] + mp[3*kENC + i]) * (1.f / kN);
  __syncthreads();
  int j = threadIdx.x;
  const float* W  = blockIdx.y ? Wc : Wh;
  const float* bb = blockIdx.y ? bc : bh;
  float acc = bb[j];
  for (int k = 0; k < kENC; k++) acc = fmaf(mf[k], W[k * kDEC + j], acc);
  (blockIdx.y ? c : h)[b * kDEC + j] = acc;
}

// ---------------- gather embeddings: Xemb[t*64+b][512] ----------------
__global__ __launch_bounds__(512) void k_gather(const float* __restrict__ emb,
        const int* __restrict__ captions, unsigned short* __restrict__ Xemb){
  int m = blockIdx.x;
  int t = m >> 6, b = m & 63, d = threadIdx.x;
  Xemb[(size_t)m * kE + d] = f2b(emb[(size_t)captions[b * kT + t] * kE + d]);
}

// ------- generic 16x64-per-wave MFMA GEMM: C_bf16 = A[M][K] @ Bt[N][Kslice]^T -------
template<int K, int LDA, int LDB, int LDC>
__global__ __launch_bounds__(256) void k_gemm_nt(const unsigned short* __restrict__ A,
                                                 const unsigned short* __restrict__ Bt,
                                                 unsigned short* __restrict__ Cb){
  int w = threadIdx.x >> 6, lane = threadIdx.x & 63;
  int m0 = blockIdx.x * 64 + w * 16, n0 = blockIdx.y * 64;
  int lr = lane & 15, lk = (lane >> 4) * 8;
  f4 acc[4] = {};
  const unsigned short* Ap = A  + (size_t)(m0 + lr) * LDA + lk;
  const unsigned short* Bp = Bt + (size_t)(n0 + lr) * LDB + lk;
  #pragma unroll 4
  for (int k0 = 0; k0 < K; k0 += 32){
    bf8 a  = *(const bf8*)(Ap + k0);
    bf8 b0 = *(const bf8*)(Bp + k0);
    bf8 b1 = *(const bf8*)(Bp + (size_t)16 * LDB + k0);
    bf8 b2 = *(const bf8*)(Bp + (size_t)32 * LDB + k0);
    bf8 b3 = *(const bf8*)(Bp + (size_t)48 * LDB + k0);
    acc[0] = mfma16(a, b0, acc[0]); acc[1] = mfma16(a, b1, acc[1]);
    acc[2] = mfma16(a, b2, acc[2]); acc[3] = mfma16(a, b3, acc[3]);
  }
  asm volatile("s_nop 7\n\ts_nop 7");
  int orow = (lane >> 4) * 4;
  #pragma unroll
  for (int nt = 0; nt < 4; nt++)
    #pragma unroll
    for (int r = 0; r < 4; r++)
      Cb[(size_t)(m0 + orow + r) * LDC + n0 + nt*16 + lr] = f2b(acc[nt][r]);
}

// ---------------- e[r] = tanh(enc_att[r] + hWdec[b]) . att_v ----------------
__global__ __launch_bounds__(256) void k_e(const unsigned short* __restrict__ EA,
                   const float* __restrict__ hWdec,
                   const float* __restrict__ attv, float* __restrict__ e){
  int w = threadIdx.x >> 6, lane = threadIdx.x & 63;
  int r = blockIdx.x * 4 + w;
  int b = r / kN;
  u4 ev = *(const u4*)(EA + (size_t)r * kATT + lane * 8);
  const float* hp = hWdec + b * kATT + lane * 8;
  const float* ap = attv + lane * 8;
  float4 h0 = *(const float4*)hp, h1 = *(const float4*)(hp + 4);
  float4 v0 = *(const float4*)ap, v1 = *(const float4*)(ap + 4);
  float s = 0.f;
  s = fmaf(th_(bf2f((unsigned short)(ev.x & 0xffffu)) + h0.x), v0.x, s);
  s = fmaf(th_(bf2f((unsigned short)(ev.x >> 16))     + h0.y), v0.y, s);
  s = fmaf(th_(bf2f((unsigned short)(ev.y & 0xffffu)) + h0.z), v0.z, s);
  s = fmaf(th_(bf2f((unsigned short)(ev.y >> 16))     + h0.w), v0.w, s);
  s = fmaf(th_(bf2f((unsigned short)(ev.z & 0xffffu)) + h1.x), v1.x, s);
  s = fmaf(th_(bf2f((unsigned short)(ev.z >> 16))     + h1.y), v1.y, s);
  s = fmaf(th_(bf2f((unsigned short)(ev.w & 0xffffu)) + h1.z), v1.z, s);
  s = fmaf(th_(bf2f((unsigned short)(ev.w >> 16))     + h1.w), v1.w, s);
  #pragma unroll
  for (int off = 32; off; off >>= 1) s += __shfl_xor(s, off, 64);
  if (lane == 0) e[r] = s;
}

// ---------------- softmax (redundant per block) + context chunk ----------------
__global__ __launch_bounds__(256) void k_ctx(const float* __restrict__ e,
                     const unsigned short* __restrict__ featb,
                     unsigned short* __restrict__ Xb, float* __restrict__ alphas, int t){
  __shared__ float al[kN];
  __shared__ float red[256];
  __shared__ float cred[4][64][8];
  int b = blockIdx.x, q = blockIdx.y, tid = threadIdx.x;
  float ev = (tid < kN) ? e[b * kN + tid] : -1e30f;
  red[tid] = ev; __syncthreads();
  for (int off = 128; off; off >>= 1){ if (tid < off) red[tid] = fmaxf(red[tid], red[tid + off]); __syncthreads(); }
  float mx = red[0]; __syncthreads();
  float ex = (tid < kN) ? __expf(ev - mx) : 0.f;
  red[tid] = ex; __syncthreads();
  for (int off = 128; off; off >>= 1){ if (tid < off) red[tid] += red[tid + off]; __syncthreads(); }
  float inv = 1.f / red[0];
  if (tid < kN){
    float a = ex * inv;
    al[tid] = a;
    if (q == 0) alphas[((size_t)b * kTS + t) * kN + tid] = a;
  }
  __syncthreads();
  int g = tid & 63, nq = tid >> 6;
  int d0 = q * 512 + g * 8;
  const unsigned short* fp = featb + (size_t)b * kN * kENC + d0;
  float c[8] = {0.f,0.f,0.f,0.f,0.f,0.f,0.f,0.f};
  int nbeg = nq * 49, nend = nbeg + 49;
  #pragma unroll 7
  for (int n = nbeg; n < nend; ++n){
    u4 v = *(const u4*)(fp + (size_t)n * kENC);
    float a = al[n];
    c[0] = fmaf(bf2f((unsigned short)(v.x & 0xffffu)), a, c[0]);
    c[1] = fmaf(bf2f((unsigned short)(v.x >> 16)),     a, c[1]);
    c[2] = fmaf(bf2f((unsigned short)(v.y & 0xffffu)), a, c[2]);
    c[3] = fmaf(bf2f((unsigned short)(v.y >> 16)),     a, c[3]);
    c[4] = fmaf(bf2f((unsigned short)(v.z & 0xffffu)), a, c[4]);
    c[5] = fmaf(bf2f((unsigned short)(v.z >> 16)),     a, c[5]);
    c[6] = fmaf(bf2f((unsigned short)(v.w & 0xffffu)), a, c[6]);
    c[7] = fmaf(bf2f((unsigned short)(v.w >> 16)),     a, c[7]);
  }
  if (nq){
    #pragma unroll
    for (int j = 0; j < 8; j++) cred[nq][g][j] = c[j];
  }
  __syncthreads();
  if (nq == 0){
    unsigned outw[4];
    #pragma unroll
    for (int j = 0; j < 4; j++){
      float lo = c[2*j]   + cred[1][g][2*j]   + cred[2][g][2*j]   + cred[3][g][2*j];
      float hi = c[2*j+1] + cred[1][g][2*j+1] + cred[2][g][2*j+1] + cred[3][g][2*j+1];
      outw[j] = ((unsigned)f2b(hi) << 16) | (unsigned)f2b(lo);
    }
    *(u4*)(Xb + (size_t)b * kKG + d0) = *(u4*)outw;
  }
}

// ---------------- per-step gates GEMM split-K over K=2560 ----------------
__global__ __launch_bounds__(256) void k_gates(const unsigned short* __restrict__ X,
        const unsigned short* __restrict__ Wih, const unsigned short* __restrict__ Whh,
        float* __restrict__ gpart){
  int w = threadIdx.x >> 6, lane = threadIdx.x & 63;
  int n0 = blockIdx.x * 64 + w * 16, ks = blockIdx.y;
  int lr = lane & 15, lk = (lane >> 4) * 8;
  int nrow = n0 + lr;
  f4 acc[4] = {};
  const unsigned short* Xp = X + (size_t)lr * kKG + ks * kKSP + lk;
  #pragma unroll 2
  for (int kt = 0; kt < kKSP; kt += 32){
    int kk = ks * kKSP + kt + lk;
    bf8 a0 = *(const bf8*)(Xp + kt);
    bf8 a1 = *(const bf8*)(Xp + 16 * kKG + kt);
    bf8 a2 = *(const bf8*)(Xp + 32 * kKG + kt);
    bf8 a3 = *(const bf8*)(Xp + 48 * kKG + kt);
    const unsigned short* bp = (kk < kENC) ? (Wih + (size_t)nrow * kKIH + kE + kk)
                                           : (Whh + (size_t)nrow * kDEC + (kk - kENC));
    bf8 b = *(const bf8*)bp;
    acc[0] = mfma16(a0, b, acc[0]); acc[1] = mfma16(a1, b, acc[1]);
    acc[2] = mfma16(a2, b, acc[2]); acc[3] = mfma16(a3, b, acc[3]);
  }
  asm volatile("s_nop 7\n\ts_nop 7");
  float* gp = gpart + (size_t)ks * kB * kG;
  int orow = (lane >> 4) * 4;
  #pragma unroll
  for (int mt = 0; mt < 4; mt++)
    #pragma unroll
    for (int r = 0; r < 4; r++)
      gp[(size_t)(mt*16 + orow + r) * kG + n0 + lr] = acc[mt][r];
}

// ---------------- LSTM pointwise + h stores + hWdec ----------------
__global__ __launch_bounds__(512) void k_lstm(const float* __restrict__ gpart,
      const unsigned short* __restrict__ Gxb,
      const float* __restrict__ bih, const float* __restrict__ bhh,
      float* __restrict__ c, unsigned short* __restrict__ Xb,
      unsigned short* __restrict__ Hall,
      const float* __restrict__ WdecT, float* __restrict__ hWdec, int t){
  __shared__ float hl[kDEC];
  int b = blockIdx.x, d = threadIdx.x;
  int m = t * kB + b;
  float gi = 0.f, gf = 0.f, gg = 0.f, go = 0.f;
  for (int ks = 0; ks < kSPL; ks++){
    const float* gp = gpart + ((size_t)ks * kB + b) * kG;
    gi += gp[d]; gf += gp[kDEC + d]; gg += gp[2*kDEC + d]; go += gp[3*kDEC + d];
  }
  const unsigned short* gx = Gxb + (size_t)m * kG;
  gi += bf2f(gx[d])          + bih[d]          + bhh[d];
  gf += bf2f(gx[kDEC + d])   + bih[kDEC + d]   + bhh[kDEC + d];
  gg += bf2f(gx[2*kDEC + d]) + bih[2*kDEC + d] + bhh[2*kDEC + d];
  go += bf2f(gx[3*kDEC + d]) + bih[3*kDEC + d] + bhh[3*kDEC + d];
  float cn = sg_(gf) * c[b*kDEC + d] + sg_(gi) * th_(gg);
  float hn = sg_(go) * th_(cn);
  c[b*kDEC + d] = cn;
  hl[d] = hn;
  unsigned short hb = f2b(hn);
  Xb[(size_t)b*kKG + kENC + d] = hb;
  Hall[((size_t)b*kTS + t)*kDEC + d] = hb;
  __syncthreads();
  const float* wr = WdecT + (size_t)d * kATT;
  float a = 0.f;
  #pragma unroll 8
  for (int kk = 0; kk < kATT; kk += 4){
    float4 wv = *(const float4*)(wr + kk);
    a = fmaf(wv.x, hl[kk + 0], a);
    a = fmaf(wv.y, hl[kk + 1], a);
    a = fmaf(wv.z, hl[kk + 2], a);
    a = fmaf(wv.w, hl[kk + 3], a);
  }
  hWdec[b * kATT + d] = a;
}

// ---------------- initial h0 -> Xb + hWdec ----------------
__global__ __launch_bounds__(512) void k_prep(const float* __restrict__ h0,
      unsigned short* __restrict__ Xb,
      const float* __restrict__ WdecT, float* __restrict__ hWdec){
  __shared__ float hl[kDEC];
  int b = blockIdx.x, d = threadIdx.x;
  float hv = h0[b*kDEC + d];
  hl[d] = hv;
  Xb[(size_t)b*kKG + kENC + d] = f2b(hv);
  __syncthreads();
  const float* wr = WdecT + (size_t)d * kATT;
  float a = 0.f;
  #pragma unroll 8
  for (int kk = 0; kk < kATT; kk += 4){
    float4 wv = *(const float4*)(wr + kk);
    a = fmaf(wv.x, hl[kk + 0], a);
    a = fmaf(wv.y, hl[kk + 1], a);
    a = fmaf(wv.z, hl[kk + 2], a);
    a = fmaf(wv.w, hl[kk + 3], a);
  }
  hWdec[b * kATT + d] = a;
}

// ---------------- batched out-projection: full B-tile staged in LDS ----------------
constexpr int kBP = 520;    // B LDS row pitch in shorts (row offset = 4 banks)
constexpr int kLDW = 132;   // output-staging pitch (aliased onto Bs)
__global__ __launch_bounds__(512) void k_bigout(const unsigned short* __restrict__ Hall,
        const unsigned short* __restrict__ Wt,  // [32000][512]
        const float* __restrict__ bias, float* __restrict__ preds){
  __shared__ __align__(16) unsigned short Bs[128][kBP];   // 133 KB
  int w = threadIdx.x >> 6, lane = threadIdx.x & 63;
  int m0 = blockIdx.x * 256;              // 8 m-blocks co-run, share B via L3
  int n0 = blockIdx.y * 128;
  int lr = lane & 15, lk = (lane >> 4) * 8;
  // ---- stage B-tile: 128 rows x 512 k (131 KB), coalesced u4 loads ----
  {
    int tid = threadIdx.x;
    #pragma unroll
    for (int j = 0; j < 16; j++){
      int f = tid + j * 512;            // 0..8191
      int row = f >> 6, kc = f & 63;    // 64 u4 per row
      u4 v = *(const u4*)(Wt + (size_t)(n0 + row) * kDEC + kc * 8);
      *(u4*)(&Bs[row][kc * 8]) = v;
    }
  }
  f4 acc[2][8];
  #pragma unroll
  for (int nt = 0; nt < 8; nt++){
    float bv = bias[n0 + nt*16 + lr];
    acc[0][nt] = (f4){bv, bv, bv, bv};
    acc[1][nt] = (f4){bv, bv, bv, bv};
  }
  __syncthreads();
  const unsigned short* Ap = Hall + (size_t)(m0 + w*32 + lr) * kDEC + lk;
  #pragma unroll 2
  for (int k0 = 0; k0 < kDEC; k0 += 32){
    bf8 a0 = *(const bf8*)(Ap + k0);
    bf8 a1 = *(const bf8*)(Ap + 16*kDEC + k0);
    #pragma unroll
    for (int nt = 0; nt < 8; nt++){
      bf8 b = *(const bf8*)(&Bs[nt*16 + lr][k0 + lk]);
      acc[0][nt] = mfma16(a0, b, acc[0][nt]);
      acc[1][nt] = mfma16(a1, b, acc[1][nt]);
    }
  }
  asm volatile("s_nop 7\n\ts_nop 7");
  // ---- output staging reuses Bs memory (ordered by the barrier below) ----
  float (*st)[kLDW] = (float(*)[kLDW])(&Bs[0][0]);
  int orow = (lane >> 4) * 4;
  for (int c = 0; c < 4; c++){
    __syncthreads();
    if ((w >> 1) == c){
      int rbase = (w & 1) * 32;
      #pragma unroll
      for (int half = 0; half < 2; half++)
        #pragma unroll
        for (int nt = 0; nt < 8; nt++)
          #pragma unroll
          for (int r = 0; r < 4; r++)
            st[rbase + half*16 + orow + r][nt*16 + lr] = acc[half][nt][r];
    }
    __syncthreads();
    int mbase = m0 + c*64;
    #pragma unroll
    for (int p = 0; p < 4; p++){
      int idx = threadIdx.x + p*512;
      int row = idx >> 5, c4 = idx & 31;
      int m = mbase + row;
      if (m < kM){
        float4 v = *(const float4*)(&st[row][c4*4]);
        *(float4*)(preds + (size_t)m * kV + n0 + c4*4) = v;
      }
    }
  }
}

extern "C" void kernel_launch(void* const* d_in, const int* in_sizes, int n_in,
                              void* d_out, int out_size, void* d_ws, size_t ws_size,
                              hipStream_t stream) {
  const float* feat     = (const float*)d_in[0];
  const int*   captions = (const int*)  d_in[1];
  const float* emb      = (const float*)d_in[2];
  const float* attWenc  = (const float*)d_in[3];
  const float* attWdec  = (const float*)d_in[4];
  const float* attv     = (const float*)d_in[5];
  const float* ihW      = (const float*)d_in[6];
  const float* ihb      = (const float*)d_in[7];
  const float* icW      = (const float*)d_in[8];
  const float* icb      = (const float*)d_in[9];
  const float* Wih      = (const float*)d_in[10];
  const float* Whh      = (const float*)d_in[11];
  const float* bih      = (const float*)d_in[12];
  const float* bhh      = (const float*)d_in[13];
  const float* outW     = (const float*)d_in[14];
  const float* outb     = (const float*)d_in[15];

  float* preds  = (float*)d_out;                       // [64][31][32000] rows m'=b*31+t
  float* alphas = preds + (size_t)kB * kTS * kV;       // [64][31][196]

  char* p = (char*)d_ws;
  unsigned short* featb  = (unsigned short*)p; p += (size_t)kB*kN*kENC*2;   // 51.4 MB
  unsigned short* outWb  = (unsigned short*)p; p += (size_t)kV*kDEC*2;      // 32.8 MB
  unsigned short* Wihb   = (unsigned short*)p; p += (size_t)kG*kKIH*2;      // 10.5 MB
  unsigned short* Whhb   = (unsigned short*)p; p += (size_t)kG*kDEC*2;      //  2.1 MB
  unsigned short* attWT  = (unsigned short*)p; p += (size_t)kATT*kENC*2;    //  2.1 MB
  unsigned short* encattb= (unsigned short*)p; p += (size_t)kB*kN*kATT*2;   // 12.8 MB
  unsigned short* Gxb    = (unsigned short*)p; p += (size_t)kMP*kG*2;       //  8.4 MB
  unsigned short* Hall   = (unsigned short*)p; p += (size_t)kMP*kDEC*2;     //  2.1 MB
  unsigned short* Xemb   = Hall;   // dead before Hall is written
  unsigned short* Xb     = (unsigned short*)p; p += (size_t)kB*kKG*2;       //  0.33 MB
  float* WdecTf = (float*)p; p += (size_t)kATT*kDEC*4;                      //  1.0 MB fp32
  float* gpart  = (float*)p; p += (size_t)kSPL*kB*kG*4;                     //  4.2 MB
  float* meanp  = (float*)p; p += (size_t)kB*4*kENC*4;                      //  2.1 MB
  float* hbuf   = (float*)p; p += (size_t)kB*kDEC*4;
  float* cws    = (float*)p; p += (size_t)kB*kDEC*4;
  float* hWdec  = (float*)p; p += (size_t)kB*kATT*4;
  float* evec   = (float*)p; p += (size_t)kB*kN*4;

  k_cvtmean<<<dim3(kB, 4), 256, 0, stream>>>(feat, featb, meanp);
  k_cvt<<<(kG*kKIH/8 + 255)/256, 256, 0, stream>>>(Wih, Wihb, kG*kKIH/8);
  k_cvt<<<(kG*kDEC/8 + 255)/256, 256, 0, stream>>>(Whh, Whhb, kG*kDEC/8);
  k_tcvt<<<dim3(kATT/32, kENC/32), 256, 0, stream>>>(attWenc, attWT, kENC, kATT);
  k_tf32<<<dim3(kATT/32, kDEC/32), 256, 0, stream>>>(attWdec, WdecTf, kDEC, kATT);
  k_tcvt<<<dim3(kV/32, kDEC/32), 256, 0, stream>>>(outW, outWb, kDEC, kV);

  k_init<<<dim3(kB, 2), 512, 0, stream>>>(meanp, ihW, ihb, icW, icb, hbuf, cws);

  // Gx[m][2048] = Xemb[m][512] @ Wih[:,0:512]^T
  k_gather<<<kM, 512, 0, stream>>>(emb, captions, Xemb);
  k_gemm_nt<kE, kE, kKIH, kG><<<dim3(kMP/64, kG/64), 256, 0, stream>>>(Xemb, Wihb, Gxb);

  // enc_att = featb @ attWT^T
  k_gemm_nt<kENC, kENC, kENC, kATT><<<dim3(kB*kN/64, kATT/64), 256, 0, stream>>>(featb, attWT, encattb);

  k_prep<<<kB, 512, 0, stream>>>(hbuf, Xb, WdecTf, hWdec);

  for (int t = 0; t < kTS; ++t) {
    k_e<<<kB*kN/4, 256, 0, stream>>>(encattb, hWdec, attv, evec);
    k_ctx<<<dim3(kB, 4), 256, 0, stream>>>(evec, featb, Xb, alphas, t);
    k_gates<<<dim3(kG/64, kSPL), 256, 0, stream>>>(Xb, Wihb, Whhb, gpart);
    k_lstm<<<kB, 512, 0, stream>>>(gpart, Gxb, bih, bhh, cws, Xb, Hall,
                                   WdecTf, hWdec, t);
  }

  k_bigout<<<dim3(kMP/256, kV/128), 512, 0, stream>>>(Hall, outWb, outb, preds);
}

// Round 15
// 2202.225 us; speedup vs baseline: 1.4679x; 1.0578x over previous
//
#include <hip/hip_runtime.h>
#include <math.h>

constexpr int kB = 64, kN = 196, kENC = 2048, kDEC = 512, kE = 512, kATT = 512;
constexpr int kV = 32000, kT = 32, kTS = 31;
constexpr int kKIH = kE + kENC;        // 2560 (W_ih K)
constexpr int kKG  = kENC + kDEC;      // 2560 (per-step gates K: [ctx; h])
constexpr int kG   = 4 * kDEC;         // 2048
constexpr int kSPL = 8, kKSP = kKG / kSPL; // 320
constexpr int kM   = kTS * kB;         // 1984
constexpr int kMP  = 2048;

typedef __attribute__((ext_vector_type(8))) short bf8;
typedef __attribute__((ext_vector_type(4))) float f4;
typedef __attribute__((ext_vector_type(4))) unsigned u4;

__device__ __forceinline__ f4 mfma16(bf8 a, bf8 b, f4 c){
  asm("v_mfma_f32_16x16x32_bf16 %0, %1, %2, %0" : "+v"(c) : "v"(a), "v"(b));
  return c;
}
__device__ __forceinline__ float bf2f(unsigned short u){
  return __uint_as_float(((unsigned)u) << 16);
}
__device__ __forceinline__ unsigned short f2b(float f){
  unsigned u = __float_as_uint(f);
  u += 0x7fffu + ((u >> 16) & 1u);
  return (unsigned short)(u >> 16);
}
__device__ __forceinline__ float th_(float x){
  float e2 = __expf(2.f * x);
  return 1.f - 2.f * __builtin_amdgcn_rcpf(e2 + 1.f);
}
__device__ __forceinline__ float sg_(float x){
  return __builtin_amdgcn_rcpf(1.f + __expf(-x));
}

// ---------------- fp32 -> bf16 bulk convert ----------------
__global__ void k_cvt(const float* __restrict__ src, unsigned short* __restrict__ dst, int n8){
  int i = blockIdx.x * 256 + threadIdx.x;
  if (i >= n8) return;
  float4 a = ((const float4*)src)[2 * i];
  float4 b = ((const float4*)src)[2 * i + 1];
  union { unsigned short u[8]; uint4 v; } t;
  t.u[0] = f2b(a.x); t.u[1] = f2b(a.y); t.u[2] = f2b(a.z); t.u[3] = f2b(a.w);
  t.u[4] = f2b(b.x); t.u[5] = f2b(b.y); t.u[6] = f2b(b.z); t.u[7] = f2b(b.w);
  ((uint4*)dst)[i] = t.v;
}

// ------- features: fp32->bf16 convert + partial mean over n (fused) -------
__global__ __launch_bounds__(256) void k_cvtmean(const float* __restrict__ feat,
        unsigned short* __restrict__ featb, float* __restrict__ meanp){
  int b = blockIdx.x, nq = blockIdx.y, tid = threadIdx.x;
  int d0 = tid * 8;
  const float* fp = feat + (size_t)b * kN * kENC + d0;
  unsigned short* op = featb + (size_t)b * kN * kENC + d0;
  float s[8] = {0.f,0.f,0.f,0.f,0.f,0.f,0.f,0.f};
  int nbeg = nq * 49, nend = nbeg + 49;
  #pragma unroll 4
  for (int n = nbeg; n < nend; ++n){
    float4 a = *(const float4*)(fp + (size_t)n * kENC);
    float4 c = *(const float4*)(fp + (size_t)n * kENC + 4);
    union { unsigned short u[8]; u4 v; } t;
    t.u[0] = f2b(a.x); t.u[1] = f2b(a.y); t.u[2] = f2b(a.z); t.u[3] = f2b(a.w);
    t.u[4] = f2b(c.x); t.u[5] = f2b(c.y); t.u[6] = f2b(c.z); t.u[7] = f2b(c.w);
    *(u4*)(op + (size_t)n * kENC) = t.v;
    s[0] += a.x; s[1] += a.y; s[2] += a.z; s[3] += a.w;
    s[4] += c.x; s[5] += c.y; s[6] += c.z; s[7] += c.w;
  }
  float* mp = meanp + ((size_t)b * 4 + nq) * kENC + d0;
  #pragma unroll
  for (int j = 0; j < 8; j++) mp[j] = s[j];
}

// ---------------- fp32 [R][C] -> bf16 [C][R] ----------------
__global__ __launch_bounds__(256) void k_tcvt(const float* __restrict__ src,
                                              unsigned short* __restrict__ dst, int R, int C){
  __shared__ float t[32][33];
  int c0 = blockIdx.x * 32, r0 = blockIdx.y * 32;
  int tx = threadIdx.x & 31, ty = threadIdx.x >> 5;
  #pragma unroll
  for (int j = 0; j < 4; j++)
    t[ty + 8*j][tx] = src[(size_t)(r0 + ty + 8*j) * C + c0 + tx];
  __syncthreads();
  #pragma unroll
  for (int j = 0; j < 4; j++)
    dst[(size_t)(c0 + ty + 8*j) * R + r0 + tx] = f2b(t[tx][ty + 8*j]);
}

// ---------------- fp32 [R][C] -> fp32 [C][R] ----------------
__global__ __launch_bounds__(256) void k_tf32(const float* __restrict__ src,
                                              float* __restrict__ dst, int R, int C){
  __shared__ float t[32][33];
  int c0 = blockIdx.x * 32, r0 = blockIdx.y * 32;
  int tx = threadIdx.x & 31, ty = threadIdx.x >> 5;
  #pragma unroll
  for (int j = 0; j < 4; j++)
    t[ty + 8*j][tx] = src[(size_t)(r0 + ty + 8*j) * C + c0 + tx];
  __syncthreads();
  #pragma unroll
  for (int j = 0; j < 4; j++)
    dst[(size_t)(c0 + ty + 8*j) * R + r0 + tx] = t[tx][ty + 8*j];
}

// ---------------- h0 / c0 (sums 4 mean partials) ----------------
__global__ __launch_bounds__(512) void k_init(const float* __restrict__ meanp,
                       const float* __restrict__ Wh, const float* __restrict__ bh,
                       const float* __restrict__ Wc, const float* __restrict__ bc,
                       float* __restrict__ h, float* __restrict__ c){
  __shared__ float mf[kENC];
  int b = blockIdx.x;
  const float* mp = meanp + (size_t)b * 4 * kENC;
  for (int i = threadIdx.x; i < kENC; i += 512)
    mf[i] = (mp[i] + mp[kENC + i] + mp[2*kENC + i] + mp[3*kENC + i]) * (1.f / kN);
  __syncthreads();
  int j = threadIdx.x;
  const float* W  = blockIdx.y ? Wc : Wh;
  const float* bb = blockIdx.y ? bc : bh;
  float acc = bb[j];
  for (int k = 0; k < kENC; k++) acc = fmaf(mf[k], W[k * kDEC + j], acc);
  (blockIdx.y ? c : h)[b * kDEC + j] = acc;
}

// ---------------- gather embeddings: Xemb[t*64+b][512] ----------------
__global__ __launch_bounds__(512) void k_gather(const float* __restrict__ emb,
        const int* __restrict__ captions, unsigned short* __restrict__ Xemb){
  int m = blockIdx.x;
  int t = m >> 6, b = m & 63, d = threadIdx.x;
  Xemb[(size_t)m * kE + d] = f2b(emb[(size_t)captions[b * kT + t] * kE + d]);
}

// ------- 4x4-fragment MFMA GEMM: wave = 64 rows x 64 cols, block = 256 rows -------
// grid (M/256, N/64). 8 loads + 16 MFMAs per K-iter (4x the MFMA:load ratio).
template<int K, int LDA, int LDB, int LDC>
__global__ __launch_bounds__(256) void k_gemm4(const unsigned short* __restrict__ A,
                                               const unsigned short* __restrict__ Bt,
                                               unsigned short* __restrict__ Cb){
  int w = threadIdx.x >> 6, lane = threadIdx.x & 63;
  int m0 = blockIdx.x * 256 + w * 64, n0 = blockIdx.y * 64;
  int lr = lane & 15, lk = (lane >> 4) * 8;
  f4 acc[4][4] = {};
  const unsigned short* Ap = A  + (size_t)(m0 + lr) * LDA + lk;
  const unsigned short* Bp = Bt + (size_t)(n0 + lr) * LDB + lk;
  #pragma unroll 2
  for (int k0 = 0; k0 < K; k0 += 32){
    bf8 a0 = *(const bf8*)(Ap + k0);
    bf8 a1 = *(const bf8*)(Ap + (size_t)16 * LDA + k0);
    bf8 a2 = *(const bf8*)(Ap + (size_t)32 * LDA + k0);
    bf8 a3 = *(const bf8*)(Ap + (size_t)48 * LDA + k0);
    bf8 b0 = *(const bf8*)(Bp + k0);
    bf8 b1 = *(const bf8*)(Bp + (size_t)16 * LDB + k0);
    bf8 b2 = *(const bf8*)(Bp + (size_t)32 * LDB + k0);
    bf8 b3 = *(const bf8*)(Bp + (size_t)48 * LDB + k0);
    acc[0][0] = mfma16(a0, b0, acc[0][0]); acc[0][1] = mfma16(a0, b1, acc[0][1]);
    acc[0][2] = mfma16(a0, b2, acc[0][2]); acc[0][3] = mfma16(a0, b3, acc[0][3]);
    acc[1][0] = mfma16(a1, b0, acc[1][0]); acc[1][1] = mfma16(a1, b1, acc[1][1]);
    acc[1][2] = mfma16(a1, b2, acc[1][2]); acc[1][3] = mfma16(a1, b3, acc[1][3]);
    acc[2][0] = mfma16(a2, b0, acc[2][0]); acc[2][1] = mfma16(a2, b1, acc[2][1]);
    acc[2][2] = mfma16(a2, b2, acc[2][2]); acc[2][3] = mfma16(a2, b3, acc[2][3]);
    acc[3][0] = mfma16(a3, b0, acc[3][0]); acc[3][1] = mfma16(a3, b1, acc[3][1]);
    acc[3][2] = mfma16(a3, b2, acc[3][2]); acc[3][3] = mfma16(a3, b3, acc[3][3]);
  }
  asm volatile("s_nop 7\n\ts_nop 7");
  int orow = (lane >> 4) * 4;
  #pragma unroll
  for (int mt = 0; mt < 4; mt++)
    #pragma unroll
    for (int nt = 0; nt < 4; nt++)
      #pragma unroll
      for (int r = 0; r < 4; r++)
        Cb[(size_t)(m0 + mt*16 + orow + r) * LDC + n0 + nt*16 + lr] = f2b(acc[mt][nt][r]);
}

// ---------------- e[r] = tanh(enc_att[r] + hWdec[b]) . att_v ----------------
__global__ __launch_bounds__(256) void k_e(const unsigned short* __restrict__ EA,
                   const float* __restrict__ hWdec,
                   const float* __restrict__ attv, float* __restrict__ e){
  int w = threadIdx.x >> 6, lane = threadIdx.x & 63;
  int r = blockIdx.x * 4 + w;
  int b = r / kN;
  u4 ev = *(const u4*)(EA + (size_t)r * kATT + lane * 8);
  const float* hp = hWdec + b * kATT + lane * 8;
  const float* ap = attv + lane * 8;
  float4 h0 = *(const float4*)hp, h1 = *(const float4*)(hp + 4);
  float4 v0 = *(const float4*)ap, v1 = *(const float4*)(ap + 4);
  float s = 0.f;
  s = fmaf(th_(bf2f((unsigned short)(ev.x & 0xffffu)) + h0.x), v0.x, s);
  s = fmaf(th_(bf2f((unsigned short)(ev.x >> 16))     + h0.y), v0.y, s);
  s = fmaf(th_(bf2f((unsigned short)(ev.y & 0xffffu)) + h0.z), v0.z, s);
  s = fmaf(th_(bf2f((unsigned short)(ev.y >> 16))     + h0.w), v0.w, s);
  s = fmaf(th_(bf2f((unsigned short)(ev.z & 0xffffu)) + h1.x), v1.x, s);
  s = fmaf(th_(bf2f((unsigned short)(ev.z >> 16))     + h1.y), v1.y, s);
  s = fmaf(th_(bf2f((unsigned short)(ev.w & 0xffffu)) + h1.z), v1.z, s);
  s = fmaf(th_(bf2f((unsigned short)(ev.w >> 16))     + h1.w), v1.w, s);
  #pragma unroll
  for (int off = 32; off; off >>= 1) s += __shfl_xor(s, off, 64);
  if (lane == 0) e[r] = s;
}

// ---------------- softmax (redundant per block) + context chunk ----------------
__global__ __launch_bounds__(256) void k_ctx(const float* __restrict__ e,
                     const unsigned short* __restrict__ featb,
                     unsigned short* __restrict__ Xb, float* __restrict__ alphas, int t){
  __shared__ float al[kN];
  __shared__ float red[256];
  __shared__ float cred[4][64][8];
  int b = blockIdx.x, q = blockIdx.y, tid = threadIdx.x;
  float ev = (tid < kN) ? e[b * kN + tid] : -1e30f;
  red[tid] = ev; __syncthreads();
  for (int off = 128; off; off >>= 1){ if (tid < off) red[tid] = fmaxf(red[tid], red[tid + off]); __syncthreads(); }
  float mx = red[0]; __syncthreads();
  float ex = (tid < kN) ? __expf(ev - mx) : 0.f;
  red[tid] = ex; __syncthreads();
  for (int off = 128; off; off >>= 1){ if (tid < off) red[tid] += red[tid + off]; __syncthreads(); }
  float inv = 1.f / red[0];
  if (tid < kN){
    float a = ex * inv;
    al[tid] = a;
    if (q == 0) alphas[((size_t)b * kTS + t) * kN + tid] = a;
  }
  __syncthreads();
  int g = tid & 63, nq = tid >> 6;
  int d0 = q * 512 + g * 8;
  const unsigned short* fp = featb + (size_t)b * kN * kENC + d0;
  float c[8] = {0.f,0.f,0.f,0.f,0.f,0.f,0.f,0.f};
  int nbeg = nq * 49, nend = nbeg + 49;
  #pragma unroll 7
  for (int n = nbeg; n < nend; ++n){
    u4 v = *(const u4*)(fp + (size_t)n * kENC);
    float a = al[n];
    c[0] = fmaf(bf2f((unsigned short)(v.x & 0xffffu)), a, c[0]);
    c[1] = fmaf(bf2f((unsigned short)(v.x >> 16)),     a, c[1]);
    c[2] = fmaf(bf2f((unsigned short)(v.y & 0xffffu)), a, c[2]);
    c[3] = fmaf(bf2f((unsigned short)(v.y >> 16)),     a, c[3]);
    c[4] = fmaf(bf2f((unsigned short)(v.z & 0xffffu)), a, c[4]);
    c[5] = fmaf(bf2f((unsigned short)(v.z >> 16)),     a, c[5]);
    c[6] = fmaf(bf2f((unsigned short)(v.w & 0xffffu)), a, c[6]);
    c[7] = fmaf(bf2f((unsigned short)(v.w >> 16)),     a, c[7]);
  }
  if (nq){
    #pragma unroll
    for (int j = 0; j < 8; j++) cred[nq][g][j] = c[j];
  }
  __syncthreads();
  if (nq == 0){
    unsigned outw[4];
    #pragma unroll
    for (int j = 0; j < 4; j++){
      float lo = c[2*j]   + cred[1][g][2*j]   + cred[2][g][2*j]   + cred[3][g][2*j];
      float hi = c[2*j+1] + cred[1][g][2*j+1] + cred[2][g][2*j+1] + cred[3][g][2*j+1];
      outw[j] = ((unsigned)f2b(hi) << 16) | (unsigned)f2b(lo);
    }
    *(u4*)(Xb + (size_t)b * kKG + d0) = *(u4*)outw;
  }
}

// ---------------- per-step gates GEMM split-K over K=2560 ----------------
__global__ __launch_bounds__(256) void k_gates(const unsigned short* __restrict__ X,
        const unsigned short* __restrict__ Wih, const unsigned short* __restrict__ Whh,
        float* __restrict__ gpart){
  int w = threadIdx.x >> 6, lane = threadIdx.x & 63;
  int n0 = blockIdx.x * 64 + w * 16, ks = blockIdx.y;
  int lr = lane & 15, lk = (lane >> 4) * 8;
  int nrow = n0 + lr;
  f4 acc[4] = {};
  const unsigned short* Xp = X + (size_t)lr * kKG + ks * kKSP + lk;
  #pragma unroll 2
  for (int kt = 0; kt < kKSP; kt += 32){
    int kk = ks * kKSP + kt + lk;
    bf8 a0 = *(const bf8*)(Xp + kt);
    bf8 a1 = *(const bf8*)(Xp + 16 * kKG + kt);
    bf8 a2 = *(const bf8*)(Xp + 32 * kKG + kt);
    bf8 a3 = *(const bf8*)(Xp + 48 * kKG + kt);
    const unsigned short* bp = (kk < kENC) ? (Wih + (size_t)nrow * kKIH + kE + kk)
                                           : (Whh + (size_t)nrow * kDEC + (kk - kENC));
    bf8 b = *(const bf8*)bp;
    acc[0] = mfma16(a0, b, acc[0]); acc[1] = mfma16(a1, b, acc[1]);
    acc[2] = mfma16(a2, b, acc[2]); acc[3] = mfma16(a3, b, acc[3]);
  }
  asm volatile("s_nop 7\n\ts_nop 7");
  float* gp = gpart + (size_t)ks * kB * kG;
  int orow = (lane >> 4) * 4;
  #pragma unroll
  for (int mt = 0; mt < 4; mt++)
    #pragma unroll
    for (int r = 0; r < 4; r++)
      gp[(size_t)(mt*16 + orow + r) * kG + n0 + lr] = acc[mt][r];
}

// ---------------- LSTM pointwise + h stores + hWdec ----------------
__global__ __launch_bounds__(512) void k_lstm(const float* __restrict__ gpart,
      const unsigned short* __restrict__ Gxb,
      const float* __restrict__ bih, const float* __restrict__ bhh,
      float* __restrict__ c, unsigned short* __restrict__ Xb,
      unsigned short* __restrict__ Hall,
      const float* __restrict__ WdecT, float* __restrict__ hWdec, int t){
  __shared__ float hl[kDEC];
  int b = blockIdx.x, d = threadIdx.x;
  int m = t * kB + b;
  float gi = 0.f, gf = 0.f, gg = 0.f, go = 0.f;
  for (int ks = 0; ks < kSPL; ks++){
    const float* gp = gpart + ((size_t)ks * kB + b) * kG;
    gi += gp[d]; gf += gp[kDEC + d]; gg += gp[2*kDEC + d]; go += gp[3*kDEC + d];
  }
  const unsigned short* gx = Gxb + (size_t)m * kG;
  gi += bf2f(gx[d])          + bih[d]          + bhh[d];
  gf += bf2f(gx[kDEC + d])   + bih[kDEC + d]   + bhh[kDEC + d];
  gg += bf2f(gx[2*kDEC + d]) + bih[2*kDEC + d] + bhh[2*kDEC + d];
  go += bf2f(gx[3*kDEC + d]) + bih[3*kDEC + d] + bhh[3*kDEC + d];
  float cn = sg_(gf) * c[b*kDEC + d] + sg_(gi) * th_(gg);
  float hn = sg_(go) * th_(cn);
  c[b*kDEC + d] = cn;
  hl[d] = hn;
  unsigned short hb = f2b(hn);
  Xb[(size_t)b*kKG + kENC + d] = hb;
  Hall[((size_t)b*kTS + t)*kDEC + d] = hb;
  __syncthreads();
  const float* wr = WdecT + (size_t)d * kATT;
  float a = 0.f;
  #pragma unroll 8
  for (int kk = 0; kk < kATT; kk += 4){
    float4 wv = *(const float4*)(wr + kk);
    a = fmaf(wv.x, hl[kk + 0], a);
    a = fmaf(wv.y, hl[kk + 1], a);
    a = fmaf(wv.z, hl[kk + 2], a);
    a = fmaf(wv.w, hl[kk + 3], a);
  }
  hWdec[b * kATT + d] = a;
}

// ---------------- initial h0 -> Xb + hWdec ----------------
__global__ __launch_bounds__(512) void k_prep(const float* __restrict__ h0,
      unsigned short* __restrict__ Xb,
      const float* __restrict__ WdecT, float* __restrict__ hWdec){
  __shared__ float hl[kDEC];
  int b = blockIdx.x, d = threadIdx.x;
  float hv = h0[b*kDEC + d];
  hl[d] = hv;
  Xb[(size_t)b*kKG + kENC + d] = f2b(hv);
  __syncthreads();
  const float* wr = WdecT + (size_t)d * kATT;
  float a = 0.f;
  #pragma unroll 8
  for (int kk = 0; kk < kATT; kk += 4){
    float4 wv = *(const float4*)(wr + kk);
    a = fmaf(wv.x, hl[kk + 0], a);
    a = fmaf(wv.y, hl[kk + 1], a);
    a = fmaf(wv.z, hl[kk + 2], a);
    a = fmaf(wv.w, hl[kk + 3], a);
  }
  hWdec[b * kATT + d] = a;
}

// ---------------- batched out-projection: full B-tile staged in LDS ----------------
constexpr int kBP = 520;    // B LDS row pitch in shorts (row offset = 4 banks)
constexpr int kLDW = 132;   // output-staging pitch (aliased onto Bs)
__global__ __launch_bounds__(512) void k_bigout(const unsigned short* __restrict__ Hall,
        const unsigned short* __restrict__ Wt,  // [32000][512]
        const float* __restrict__ bias, float* __restrict__ preds){
  __shared__ __align__(16) unsigned short Bs[128][kBP];   // 133 KB
  int w = threadIdx.x >> 6, lane = threadIdx.x & 63;
  int m0 = blockIdx.x * 256;              // 8 m-blocks co-run, share B via L3
  int n0 = blockIdx.y * 128;
  int lr = lane & 15, lk = (lane >> 4) * 8;
  // ---- stage B-tile: 128 rows x 512 k (131 KB), coalesced u4 loads ----
  {
    int tid = threadIdx.x;
    #pragma unroll
    for (int j = 0; j < 16; j++){
      int f = tid + j * 512;            // 0..8191
      int row = f >> 6, kc = f & 63;    // 64 u4 per row
      u4 v = *(const u4*)(Wt + (size_t)(n0 + row) * kDEC + kc * 8);
      *(u4*)(&Bs[row][kc * 8]) = v;
    }
  }
  f4 acc[2][8];
  #pragma unroll
  for (int nt = 0; nt < 8; nt++){
    float bv = bias[n0 + nt*16 + lr];
    acc[0][nt] = (f4){bv, bv, bv, bv};
    acc[1][nt] = (f4){bv, bv, bv, bv};
  }
  __syncthreads();
  const unsigned short* Ap = Hall + (size_t)(m0 + w*32 + lr) * kDEC + lk;
  #pragma unroll 2
  for (int k0 = 0; k0 < kDEC; k0 += 32){
    bf8 a0 = *(const bf8*)(Ap + k0);
    bf8 a1 = *(const bf8*)(Ap + 16*kDEC + k0);
    #pragma unroll
    for (int nt = 0; nt < 8; nt++){
      bf8 b = *(const bf8*)(&Bs[nt*16 + lr][k0 + lk]);
      acc[0][nt] = mfma16(a0, b, acc[0][nt]);
      acc[1][nt] = mfma16(a1, b, acc[1][nt]);
    }
  }
  asm volatile("s_nop 7\n\ts_nop 7");
  // ---- output staging reuses Bs memory (ordered by the barrier below) ----
  float (*st)[kLDW] = (float(*)[kLDW])(&Bs[0][0]);
  int orow = (lane >> 4) * 4;
  for (int c = 0; c < 4; c++){
    __syncthreads();
    if ((w >> 1) == c){
      int rbase = (w & 1) * 32;
      #pragma unroll
      for (int half = 0; half < 2; half++)
        #pragma unroll
        for (int nt = 0; nt < 8; nt++)
          #pragma unroll
          for (int r = 0; r < 4; r++)
            st[rbase + half*16 + orow + r][nt*16 + lr] = acc[half][nt][r];
    }
    __syncthreads();
    int mbase = m0 + c*64;
    #pragma unroll
    for (int p = 0; p < 4; p++){
      int idx = threadIdx.x + p*512;
      int row = idx >> 5, c4 = idx & 31;
      int m = mbase + row;
      if (m < kM){
        float4 v = *(const float4*)(&st[row][c4*4]);
        *(float4*)(preds + (size_t)m * kV + n0 + c4*4) = v;
      }
    }
  }
}

extern "C" void kernel_launch(void* const* d_in, const int* in_sizes, int n_in,
                              void* d_out, int out_size, void* d_ws, size_t ws_size,
                              hipStream_t stream) {
  const float* feat     = (const float*)d_in[0];
  const int*   captions = (const int*)  d_in[1];
  const float* emb      = (const float*)d_in[2];
  const float* attWenc  = (const float*)d_in[3];
  const float* attWdec  = (const float*)d_in[4];
  const float* attv     = (const float*)d_in[5];
  const float* ihW      = (const float*)d_in[6];
  const float* ihb      = (const float*)d_in[7];
  const float* icW      = (const float*)d_in[8];
  const float* icb      = (const float*)d_in[9];
  const float* Wih      = (const float*)d_in[10];
  const float* Whh      = (const float*)d_in[11];
  const float* bih      = (const float*)d_in[12];
  const float* bhh      = (const float*)d_in[13];
  const float* outW     = (const float*)d_in[14];
  const float* outb     = (const float*)d_in[15];

  float* preds  = (float*)d_out;                       // [64][31][32000] rows m'=b*31+t
  float* alphas = preds + (size_t)kB * kTS * kV;       // [64][31][196]

  char* p = (char*)d_ws;
  unsigned short* featb  = (unsigned short*)p; p += (size_t)kB*kN*kENC*2;   // 51.4 MB
  unsigned short* outWb  = (unsigned short*)p; p += (size_t)kV*kDEC*2;      // 32.8 MB
  unsigned short* Wihb   = (unsigned short*)p; p += (size_t)kG*kKIH*2;      // 10.5 MB
  unsigned short* Whhb   = (unsigned short*)p; p += (size_t)kG*kDEC*2;      //  2.1 MB
  unsigned short* attWT  = (unsigned short*)p; p += (size_t)kATT*kENC*2;    //  2.1 MB
  unsigned short* encattb= (unsigned short*)p; p += (size_t)kB*kN*kATT*2;   // 12.8 MB
  unsigned short* Gxb    = (unsigned short*)p; p += (size_t)kMP*kG*2;       //  8.4 MB
  unsigned short* Hall   = (unsigned short*)p; p += (size_t)kMP*kDEC*2;     //  2.1 MB
  unsigned short* Xemb   = Hall;   // dead before Hall is written
  unsigned short* Xb     = (unsigned short*)p; p += (size_t)kB*kKG*2;       //  0.33 MB
  float* WdecTf = (float*)p; p += (size_t)kATT*kDEC*4;                      //  1.0 MB fp32
  float* gpart  = (float*)p; p += (size_t)kSPL*kB*kG*4;                     //  4.2 MB
  float* meanp  = (float*)p; p += (size_t)kB*4*kENC*4;                      //  2.1 MB
  float* hbuf   = (float*)p; p += (size_t)kB*kDEC*4;
  float* cws    = (float*)p; p += (size_t)kB*kDEC*4;
  float* hWdec  = (float*)p; p += (size_t)kB*kATT*4;
  float* evec   = (float*)p; p += (size_t)kB*kN*4;

  k_cvtmean<<<dim3(kB, 4), 256, 0, stream>>>(feat, featb, meanp);
  k_cvt<<<(kG*kKIH/8 + 255)/256, 256, 0, stream>>>(Wih, Wihb, kG*kKIH/8);
  k_cvt<<<(kG*kDEC/8 + 255)/256, 256, 0, stream>>>(Whh, Whhb, kG*kDEC/8);
  k_tcvt<<<dim3(kATT/32, kENC/32), 256, 0, stream>>>(attWenc, attWT, kENC, kATT);
  k_tf32<<<dim3(kATT/32, kDEC/32), 256, 0, stream>>>(attWdec, WdecTf, kDEC, kATT);
  k_tcvt<<<dim3(kV/32, kDEC/32), 256, 0, stream>>>(outW, outWb, kDEC, kV);

  k_init<<<dim3(kB, 2), 512, 0, stream>>>(meanp, ihW, ihb, icW, icb, hbuf, cws);

  // Gx[m][2048] = Xemb[m][512] @ Wih[:,0:512]^T  (4x4 tile, grid (8,32))
  k_gather<<<kM, 512, 0, stream>>>(emb, captions, Xemb);
  k_gemm4<kE, kE, kKIH, kG><<<dim3(kMP/256, kG/64), 256, 0, stream>>>(Xemb, Wihb, Gxb);

  // enc_att = featb @ attWT^T  (4x4 tile, grid (49,8))
  k_gemm4<kENC, kENC, kENC, kATT><<<dim3(kB*kN/256, kATT/64), 256, 0, stream>>>(featb, attWT, encattb);

  k_prep<<<kB, 512, 0, stream>>>(hbuf, Xb, WdecTf, hWdec);

  for (int t = 0; t < kTS; ++t) {
    k_e<<<kB*kN/4, 256, 0, stream>>>(encattb, hWdec, attv, evec);
    k_ctx<<<dim3(kB, 4), 256, 0, stream>>>(evec, featb, Xb, alphas, t);
    k_gates<<<dim3(kG/64, kSPL), 256, 0, stream>>>(Xb, Wihb, Whhb, gpart);
    k_lstm<<<kB, 512, 0, stream>>>(gpart, Gxb, bih, bhh, cws, Xb, Hall,
                                   WdecTf, hWdec, t);
  }

  k_bigout<<<dim3(kMP/256, kV/128), 512, 0, stream>>>(Hall, outWb, outb, preds);
}